// Round 1
// baseline (612.255 us; speedup 1.0000x reference)
//
#include <hip/hip_runtime.h>
#include <stdint.h>

typedef __attribute__((ext_vector_type(4))) float f32x4;
typedef __attribute__((ext_vector_type(8))) short s16x8;

// ---------- bf16 helpers ----------
__device__ __forceinline__ unsigned short bf16_rne(float f) {
    union { float f; unsigned u; } v; v.f = f;
    return (unsigned short)((v.u + 0x7fffu + ((v.u >> 16) & 1u)) >> 16);
}
__device__ __forceinline__ float bf16_to_f32(unsigned short h) {
    union { unsigned u; float f; } v; v.u = ((unsigned)h) << 16;
    return v.f;
}

// Problem dims
// B=16, C=256, CI=128, H=W=64, N=4096, NP=1024 (pooled 32x32)

// ---------------------------------------------------------------------------
// conv1x1 kernel. MODE 0: theta (no pool, split hi/lo out [b][n][o])
//                 MODE 1: phi   (pool,  split hi/lo out [b][m][o])
//                 MODE 2: g     (pool,  single     out [b][o][m])
// Block: 256 thr (4 waves). Tile: 128 n-rows x 128 o-cols, K=C=256 in 32-chunks.
// Wave w handles o-slice [w*32, w*32+32) x all 128 n rows (8 m-tiles x 2 o-tiles).
// x is staged through LDS with transpose + f32->bf16 hi/lo split.
// ---------------------------------------------------------------------------
template<int MODE>
__global__ __launch_bounds__(256) void conv_kernel(
    const float* __restrict__ x,      // [16][256][4096]
    const float* __restrict__ w,      // [128][256]
    const float* __restrict__ bias,   // [128]
    unsigned short* __restrict__ outH,
    unsigned short* __restrict__ outL)
{
    const int b   = blockIdx.y;
    const int n0  = blockIdx.x * 128;
    const int tid = threadIdx.x;
    const int wv  = tid >> 6;
    const int l   = tid & 63;
    const int lg  = l >> 4;   // lane group 0..3
    const int lc  = l & 15;   // lane col  0..15

    __shared__ __align__(16) unsigned short Ah[128][40];
    __shared__ __align__(16) unsigned short Al[128][40];

    f32x4 acc[8][2];
#pragma unroll
    for (int i = 0; i < 8; i++)
#pragma unroll
        for (int j = 0; j < 2; j++) acc[i][j] = (f32x4){0.f, 0.f, 0.f, 0.f};

    for (int kc = 0; kc < 256; kc += 32) {
        __syncthreads();
        // stage x[b][kc..kc+31][n0..n0+127] transposed into Ah/Al
#pragma unroll
        for (int i = 0; i < 16; i++) {
            int lin = i * 256 + tid;     // 0..4095
            int cc  = lin >> 7;          // 0..31
            int nn  = lin & 127;
            float v = x[((size_t)b * 256 + (kc + cc)) * 4096 + n0 + nn];
            unsigned short h = bf16_rne(v);
            Ah[nn][cc] = h;
            if (MODE != 2) Al[nn][cc] = bf16_rne(v - bf16_to_f32(h));
        }
        __syncthreads();

        // weight fragments (B operand): B[k=c][col=o], contiguous in c
        s16x8 wh[2], wl[2];
#pragma unroll
        for (int ot = 0; ot < 2; ot++) {
            int orow = wv * 32 + ot * 16 + lc;
            const float* wp = w + (size_t)orow * 256 + kc + lg * 8;
#pragma unroll
            for (int j = 0; j < 8; j++) {
                float wvv = wp[j];
                unsigned short h = bf16_rne(wvv);
                wh[ot][j] = (short)h;
                if (MODE != 2) wl[ot][j] = (short)bf16_rne(wvv - bf16_to_f32(h));
            }
        }

#pragma unroll
        for (int mt = 0; mt < 8; mt++) {
            s16x8 ah = *(const s16x8*)&Ah[mt * 16 + lc][lg * 8];
            s16x8 al;
            if (MODE != 2) al = *(const s16x8*)&Al[mt * 16 + lc][lg * 8];
#pragma unroll
            for (int ot = 0; ot < 2; ot++) {
                acc[mt][ot] = __builtin_amdgcn_mfma_f32_16x16x32_bf16(ah, wh[ot], acc[mt][ot], 0, 0, 0);
                if (MODE != 2) {
                    acc[mt][ot] = __builtin_amdgcn_mfma_f32_16x16x32_bf16(ah, wl[ot], acc[mt][ot], 0, 0, 0);
                    acc[mt][ot] = __builtin_amdgcn_mfma_f32_16x16x32_bf16(al, wh[ot], acc[mt][ot], 0, 0, 0);
                }
            }
        }
    }

    if (MODE == 0) {
        // theta: out [b][n][o] split planes
#pragma unroll
        for (int mt = 0; mt < 8; mt++)
#pragma unroll
            for (int ot = 0; ot < 2; ot++) {
                int o = wv * 32 + ot * 16 + lc;
                float bs = bias[o];
#pragma unroll
                for (int r = 0; r < 4; r++) {
                    int n = n0 + mt * 16 + lg * 4 + r;
                    float v = acc[mt][ot][r] + bs;
                    unsigned short h = bf16_rne(v);
                    size_t idx = ((size_t)b * 4096 + n) * 128 + o;
                    outH[idx] = h;
                    outL[idx] = bf16_rne(v - bf16_to_f32(h));
                }
            }
    } else {
        // pooled: tile covers image rows {2*blk, 2*blk+1}; pooled pos m = blk*32+pw
        const int mbase = blockIdx.x * 32;
#pragma unroll
        for (int mt = 0; mt < 4; mt++)
#pragma unroll
            for (int ot = 0; ot < 2; ot++) {
                int o = wv * 32 + ot * 16 + lc;
                float bs = bias[o];
#pragma unroll
                for (int pair = 0; pair < 2; pair++) {
                    float v = fmaxf(fmaxf(acc[mt][ot][2 * pair], acc[mt][ot][2 * pair + 1]),
                                    fmaxf(acc[mt + 4][ot][2 * pair], acc[mt + 4][ot][2 * pair + 1])) + bs;
                    int pw = mt * 8 + lg * 2 + pair;
                    int m  = mbase + pw;
                    if (MODE == 1) {
                        unsigned short h = bf16_rne(v);
                        size_t idx = ((size_t)b * 1024 + m) * 128 + o;
                        outH[idx] = h;
                        outL[idx] = bf16_rne(v - bf16_to_f32(h));
                    } else {
                        outH[((size_t)b * 128 + o) * 1024 + m] = bf16_rne(v);
                    }
                }
            }
    }
}

// ---------------------------------------------------------------------------
// Attention kernel: per (batch, 16-row Q tile). 4 waves; wave w owns cols
// [w*256, w*256+256) of the 1024 K positions for QK^T. Softmax in registers
// (shfl_xor within 16-lane groups + LDS across waves). P -> LDS bf16, then PV.
// QK^T uses split-bf16 (hh + hl + lh) for ~fp32 logit precision.
// ---------------------------------------------------------------------------
__global__ __launch_bounds__(256) void attn_kernel(
    const unsigned short* __restrict__ thH,  // [16][4096][128]
    const unsigned short* __restrict__ thL,
    const unsigned short* __restrict__ phH,  // [16][1024][128]
    const unsigned short* __restrict__ phL,
    const unsigned short* __restrict__ gp,   // [16][128][1024]  (V^T)
    unsigned short* __restrict__ y)          // [16][4096][128]
{
    const int b   = blockIdx.y;
    const int n0  = blockIdx.x * 16;
    const int tid = threadIdx.x;
    const int wv  = tid >> 6;
    const int l   = tid & 63;
    const int lg  = l >> 4;
    const int lc  = l & 15;

    __shared__ __align__(16) unsigned short P[16][1032];
    __shared__ float redA[4][16];
    __shared__ float redB[4][16];

    // Q fragments (rows n0+lc, k contiguous)
    s16x8 qh[4], ql[4];
    {
        const unsigned short* qb  = thH + ((size_t)b * 4096 + n0 + lc) * 128 + lg * 8;
        const unsigned short* qbl = thL + ((size_t)b * 4096 + n0 + lc) * 128 + lg * 8;
#pragma unroll
        for (int ks = 0; ks < 4; ks++) {
            qh[ks] = *(const s16x8*)(qb + ks * 32);
            ql[ks] = *(const s16x8*)(qbl + ks * 32);
        }
    }

    f32x4 acc[16];
#pragma unroll
    for (int ct = 0; ct < 16; ct++) acc[ct] = (f32x4){0.f, 0.f, 0.f, 0.f};

#pragma unroll
    for (int ct = 0; ct < 16; ct++) {
        int m0 = wv * 256 + ct * 16;
        const unsigned short* kb  = phH + ((size_t)b * 1024 + m0 + lc) * 128 + lg * 8;
        const unsigned short* kbl = phL + ((size_t)b * 1024 + m0 + lc) * 128 + lg * 8;
#pragma unroll
        for (int ks = 0; ks < 4; ks++) {
            s16x8 kh = *(const s16x8*)(kb + ks * 32);
            s16x8 kl = *(const s16x8*)(kbl + ks * 32);
            acc[ct] = __builtin_amdgcn_mfma_f32_16x16x32_bf16(qh[ks], kh, acc[ct], 0, 0, 0);
            acc[ct] = __builtin_amdgcn_mfma_f32_16x16x32_bf16(qh[ks], kl, acc[ct], 0, 0, 0);
            acc[ct] = __builtin_amdgcn_mfma_f32_16x16x32_bf16(ql[ks], kh, acc[ct], 0, 0, 0);
        }
    }

    // ---- softmax over 1024 cols, rows = lg*4 + r ----
    float pm[4];
#pragma unroll
    for (int r = 0; r < 4; r++) {
        float m = acc[0][r];
#pragma unroll
        for (int ct = 1; ct < 16; ct++) m = fmaxf(m, acc[ct][r]);
        pm[r] = m;
    }
#pragma unroll
    for (int d = 1; d < 16; d <<= 1)
#pragma unroll
        for (int r = 0; r < 4; r++) pm[r] = fmaxf(pm[r], __shfl_xor(pm[r], d, 64));
    if (lc == 0) {
#pragma unroll
        for (int r = 0; r < 4; r++) redA[wv][lg * 4 + r] = pm[r];
    }
    __syncthreads();
    float M[4];
#pragma unroll
    for (int r = 0; r < 4; r++) {
        int row = lg * 4 + r;
        M[r] = fmaxf(fmaxf(redA[0][row], redA[1][row]), fmaxf(redA[2][row], redA[3][row]));
    }
    float ps[4] = {0.f, 0.f, 0.f, 0.f};
#pragma unroll
    for (int ct = 0; ct < 16; ct++)
#pragma unroll
        for (int r = 0; r < 4; r++) {
            float e = __expf(acc[ct][r] - M[r]);
            acc[ct][r] = e;
            ps[r] += e;
        }
#pragma unroll
    for (int d = 1; d < 16; d <<= 1)
#pragma unroll
        for (int r = 0; r < 4; r++) ps[r] += __shfl_xor(ps[r], d, 64);
    if (lc == 0) {
#pragma unroll
        for (int r = 0; r < 4; r++) redB[wv][lg * 4 + r] = ps[r];
    }
    __syncthreads();
    float inv[4];
#pragma unroll
    for (int r = 0; r < 4; r++) {
        int row = lg * 4 + r;
        inv[r] = 1.0f / (redB[0][row] + redB[1][row] + redB[2][row] + redB[3][row]);
    }
#pragma unroll
    for (int ct = 0; ct < 16; ct++)
#pragma unroll
        for (int r = 0; r < 4; r++)
            P[lg * 4 + r][wv * 256 + ct * 16 + lc] = bf16_rne(acc[ct][r] * inv[r]);
    __syncthreads();

    // ---- PV: out cols [wv*32, wv*32+32) ----
    f32x4 o0 = (f32x4){0.f, 0.f, 0.f, 0.f};
    f32x4 o1 = (f32x4){0.f, 0.f, 0.f, 0.f};
#pragma unroll
    for (int ks = 0; ks < 32; ks++) {
        s16x8 pa = *(const s16x8*)&P[lc][ks * 32 + lg * 8];
        const unsigned short* vb = gp + ((size_t)b * 128 + wv * 32 + lc) * 1024 + ks * 32 + lg * 8;
        s16x8 v0 = *(const s16x8*)(vb);
        s16x8 v1 = *(const s16x8*)(vb + (size_t)16 * 1024);
        o0 = __builtin_amdgcn_mfma_f32_16x16x32_bf16(pa, v0, o0, 0, 0, 0);
        o1 = __builtin_amdgcn_mfma_f32_16x16x32_bf16(pa, v1, o1, 0, 0, 0);
    }
#pragma unroll
    for (int r = 0; r < 4; r++) {
        int n = n0 + lg * 4 + r;
        size_t base = ((size_t)b * 4096 + n) * 128;
        y[base + wv * 32 + lc]      = bf16_rne(o0[r]);
        y[base + wv * 32 + 16 + lc] = bf16_rne(o1[r]);
    }
}

// ---------------------------------------------------------------------------
// W conv: W_y[b][o][n] = sum_ci W_w[o][ci] * y[b][n][ci] + W_b[o]   (bf16 out)
// Block 256 thr; tile 64 o x 256 n; wave w owns n-slice w*64.
// ---------------------------------------------------------------------------
__global__ __launch_bounds__(256) void wconv_kernel(
    const unsigned short* __restrict__ y,   // [16][4096][128]
    const float* __restrict__ Ww,           // [256][128]
    const float* __restrict__ Wb,           // [256]
    unsigned short* __restrict__ wy)        // [16][256][4096]
{
    const int b   = blockIdx.z;
    const int o0  = blockIdx.x * 64;
    const int nb  = blockIdx.y * 256;
    const int tid = threadIdx.x;
    const int wv  = tid >> 6;
    const int l   = tid & 63;
    const int lg  = l >> 4;
    const int lc  = l & 15;
    const int n0  = nb + wv * 64;

    f32x4 acc[4][4]; // [ot][nt]
#pragma unroll
    for (int i = 0; i < 4; i++)
#pragma unroll
        for (int j = 0; j < 4; j++) acc[i][j] = (f32x4){0.f, 0.f, 0.f, 0.f};

#pragma unroll
    for (int ks = 0; ks < 4; ks++) {
        s16x8 a[4];
#pragma unroll
        for (int ot = 0; ot < 4; ot++) {
            const float* wp = Ww + (size_t)(o0 + ot * 16 + lc) * 128 + ks * 32 + lg * 8;
#pragma unroll
            for (int j = 0; j < 8; j++) a[ot][j] = (short)bf16_rne(wp[j]);
        }
#pragma unroll
        for (int nt = 0; nt < 4; nt++) {
            s16x8 bf = *(const s16x8*)(y + ((size_t)b * 4096 + n0 + nt * 16 + lc) * 128 + ks * 32 + lg * 8);
#pragma unroll
            for (int ot = 0; ot < 4; ot++)
                acc[ot][nt] = __builtin_amdgcn_mfma_f32_16x16x32_bf16(a[ot], bf, acc[ot][nt], 0, 0, 0);
        }
    }
#pragma unroll
    for (int ot = 0; ot < 4; ot++) {
#pragma unroll
        for (int r = 0; r < 4; r++) {
            int o = o0 + ot * 16 + lg * 4 + r;
            float bsv = Wb[o];
#pragma unroll
            for (int nt = 0; nt < 4; nt++) {
                float v = acc[ot][nt][r] + bsv;
                wy[((size_t)b * 256 + o) * 4096 + n0 + nt * 16 + lc] = bf16_rne(v);
            }
        }
    }
}

// ---------------------------------------------------------------------------
// BN stats: one block per channel o; sums over [b][o][:] -> scale/shift
// ---------------------------------------------------------------------------
__global__ __launch_bounds__(256) void stats_kernel(
    const unsigned short* __restrict__ wy,  // [16][256][4096]
    const float* __restrict__ gamma, const float* __restrict__ beta,
    float* __restrict__ scale, float* __restrict__ shift)
{
    const int o = blockIdx.x;
    const int t = threadIdx.x;
    float s1 = 0.f, s2 = 0.f;
    for (int b = 0; b < 16; b++) {
        const unsigned short* p = wy + ((size_t)b * 256 + o) * 4096;
#pragma unroll
        for (int i = 0; i < 4; i++) {
            uint2 u = *(const uint2*)(p + i * 1024 + t * 4);
            float v0 = bf16_to_f32((unsigned short)(u.x & 0xffff));
            float v1 = bf16_to_f32((unsigned short)(u.x >> 16));
            float v2 = bf16_to_f32((unsigned short)(u.y & 0xffff));
            float v3 = bf16_to_f32((unsigned short)(u.y >> 16));
            s1 += v0 + v1 + v2 + v3;
            s2 += v0 * v0 + v1 * v1 + v2 * v2 + v3 * v3;
        }
    }
#pragma unroll
    for (int d = 1; d < 64; d <<= 1) { s1 += __shfl_xor(s1, d, 64); s2 += __shfl_xor(s2, d, 64); }
    __shared__ float rs1[4], rs2[4];
    if ((t & 63) == 0) { rs1[t >> 6] = s1; rs2[t >> 6] = s2; }
    __syncthreads();
    if (t == 0) {
        float S1 = rs1[0] + rs1[1] + rs1[2] + rs1[3];
        float S2 = rs2[0] + rs2[1] + rs2[2] + rs2[3];
        const float cnt = 16.0f * 4096.0f;
        float mean = S1 / cnt;
        float var  = S2 / cnt - mean * mean;
        float sc = gamma[o] * rsqrtf(var + 1e-5f);
        scale[o] = sc;
        shift[o] = beta[o] - mean * sc;
    }
}

// ---------------------------------------------------------------------------
// Final: z = scale[c]*W_y + shift[c] + x ; out[0] = inp0
// ---------------------------------------------------------------------------
__global__ __launch_bounds__(256) void final_kernel(
    const unsigned short* __restrict__ wy,
    const float* __restrict__ x,
    const float* __restrict__ scale, const float* __restrict__ shift,
    const float* __restrict__ inp0,
    float* __restrict__ out)
{
    if (blockIdx.x == 0 && threadIdx.x == 0) out[0] = inp0[0];
    float* z = out + 1;
    const size_t total4 = (size_t)16 * 256 * 4096 / 4;
    for (size_t v = (size_t)blockIdx.x * 256 + threadIdx.x; v < total4; v += (size_t)gridDim.x * 256) {
        size_t e = v * 4;
        int c = (int)((e >> 12) & 255);
        uint2 u = *(const uint2*)(wy + e);
        float4 xv = *(const float4*)(x + e);
        float sc = scale[c], sh = shift[c];
        float z0 = sc * bf16_to_f32((unsigned short)(u.x & 0xffff)) + sh + xv.x;
        float z1 = sc * bf16_to_f32((unsigned short)(u.x >> 16))    + sh + xv.y;
        float z2 = sc * bf16_to_f32((unsigned short)(u.y & 0xffff)) + sh + xv.z;
        float z3 = sc * bf16_to_f32((unsigned short)(u.y >> 16))    + sh + xv.w;
        z[e + 0] = z0; z[e + 1] = z1; z[e + 2] = z2; z[e + 3] = z3;
    }
}

// ---------------------------------------------------------------------------
extern "C" void kernel_launch(void* const* d_in, const int* in_sizes, int n_in,
                              void* d_out, int out_size, void* d_ws, size_t ws_size,
                              hipStream_t stream) {
    const float* inp0  = (const float*)d_in[0];
    const float* x     = (const float*)d_in[1];
    const float* g_w   = (const float*)d_in[2];
    const float* g_b   = (const float*)d_in[3];
    const float* th_w  = (const float*)d_in[4];
    const float* th_b  = (const float*)d_in[5];
    const float* ph_w  = (const float*)d_in[6];
    const float* ph_b  = (const float*)d_in[7];
    const float* W_w   = (const float*)d_in[8];
    const float* W_b   = (const float*)d_in[9];
    const float* gamma = (const float*)d_in[10];
    const float* beta  = (const float*)d_in[11];

    char* ws = (char*)d_ws;
    const size_t MB = 1048576;
    unsigned short* thH = (unsigned short*)(ws);                  // 16 MB
    unsigned short* thL = (unsigned short*)(ws + 16 * MB);        // 16 MB
    unsigned short* phH = (unsigned short*)(ws + 32 * MB);        // 4 MB
    unsigned short* phL = (unsigned short*)(ws + 36 * MB);        // 4 MB
    unsigned short* gpv = (unsigned short*)(ws + 40 * MB);        // 4 MB
    unsigned short* yv  = (unsigned short*)(ws + 44 * MB);        // 16 MB
    unsigned short* wy  = (unsigned short*)(ws + 60 * MB);        // 32 MB
    float* scaleb       = (float*)(ws + 92 * MB);                 // 1 KB
    float* shiftb       = (float*)(ws + 92 * MB + 1024);          // 1 KB

    conv_kernel<0><<<dim3(32, 16), 256, 0, stream>>>(x, th_w, th_b, thH, thL);
    conv_kernel<1><<<dim3(32, 16), 256, 0, stream>>>(x, ph_w, ph_b, phH, phL);
    conv_kernel<2><<<dim3(32, 16), 256, 0, stream>>>(x, g_w, g_b, gpv, gpv);
    attn_kernel<<<dim3(256, 16), 256, 0, stream>>>(thH, thL, phH, phL, gpv, yv);
    wconv_kernel<<<dim3(4, 16, 16), 256, 0, stream>>>(yv, W_w, W_b, wy);
    stats_kernel<<<dim3(256), 256, 0, stream>>>(wy, gamma, beta, scaleb, shiftb);
    final_kernel<<<dim3(2048), 256, 0, stream>>>(wy, x, scaleb, shiftb, inp0, (float*)d_out);
}

// Round 2
// 545.370 us; speedup vs baseline: 1.1226x; 1.1226x over previous
//
#include <hip/hip_runtime.h>
#include <stdint.h>

typedef __attribute__((ext_vector_type(4))) float f32x4;
typedef __attribute__((ext_vector_type(8))) short s16x8;

// ---------- bf16 helpers ----------
__device__ __forceinline__ unsigned short bf16_rne(float f) {
    union { float f; unsigned u; } v; v.f = f;
    return (unsigned short)((v.u + 0x7fffu + ((v.u >> 16) & 1u)) >> 16);
}
__device__ __forceinline__ float bf16_to_f32(unsigned short h) {
    union { unsigned u; float f; } v; v.u = ((unsigned)h) << 16;
    return v.f;
}

// Problem dims: B=16, C=256, CI=128, H=W=64, N=4096, NP=1024 (pooled 32x32)

// ---------------------------------------------------------------------------
// conv1x1 kernel. MODE 0: theta (no pool, split hi/lo out [b][n][o])
//                 MODE 1: phi   (pool,  split hi/lo out [b][m][o])
//                 MODE 2: g     (pool,  single     out [b][o][m])
// ---------------------------------------------------------------------------
template<int MODE>
__global__ __launch_bounds__(256) void conv_kernel(
    const float* __restrict__ x,      // [16][256][4096]
    const float* __restrict__ w,      // [128][256]
    const float* __restrict__ bias,   // [128]
    unsigned short* __restrict__ outH,
    unsigned short* __restrict__ outL)
{
    const int b   = blockIdx.y;
    const int n0  = blockIdx.x * 128;
    const int tid = threadIdx.x;
    const int wv  = tid >> 6;
    const int l   = tid & 63;
    const int lg  = l >> 4;   // lane group 0..3
    const int lc  = l & 15;   // lane col  0..15

    __shared__ __align__(16) unsigned short Ah[128][40];
    __shared__ __align__(16) unsigned short Al[128][40];

    f32x4 acc[8][2];
#pragma unroll
    for (int i = 0; i < 8; i++)
#pragma unroll
        for (int j = 0; j < 2; j++) acc[i][j] = (f32x4){0.f, 0.f, 0.f, 0.f};

    for (int kc = 0; kc < 256; kc += 32) {
        __syncthreads();
#pragma unroll
        for (int i = 0; i < 16; i++) {
            int lin = i * 256 + tid;     // 0..4095
            int cc  = lin >> 7;          // 0..31
            int nn  = lin & 127;
            float v = x[((size_t)b * 256 + (kc + cc)) * 4096 + n0 + nn];
            unsigned short h = bf16_rne(v);
            Ah[nn][cc] = h;
            if (MODE != 2) Al[nn][cc] = bf16_rne(v - bf16_to_f32(h));
        }
        __syncthreads();

        s16x8 wh[2], wl[2];
#pragma unroll
        for (int ot = 0; ot < 2; ot++) {
            int orow = wv * 32 + ot * 16 + lc;
            const float* wp = w + (size_t)orow * 256 + kc + lg * 8;
#pragma unroll
            for (int j = 0; j < 8; j++) {
                float wvv = wp[j];
                unsigned short h = bf16_rne(wvv);
                wh[ot][j] = (short)h;
                if (MODE != 2) wl[ot][j] = (short)bf16_rne(wvv - bf16_to_f32(h));
            }
        }

#pragma unroll
        for (int mt = 0; mt < 8; mt++) {
            s16x8 ah = *(const s16x8*)&Ah[mt * 16 + lc][lg * 8];
            s16x8 al;
            if (MODE != 2) al = *(const s16x8*)&Al[mt * 16 + lc][lg * 8];
#pragma unroll
            for (int ot = 0; ot < 2; ot++) {
                acc[mt][ot] = __builtin_amdgcn_mfma_f32_16x16x32_bf16(ah, wh[ot], acc[mt][ot], 0, 0, 0);
                if (MODE != 2) {
                    acc[mt][ot] = __builtin_amdgcn_mfma_f32_16x16x32_bf16(ah, wl[ot], acc[mt][ot], 0, 0, 0);
                    acc[mt][ot] = __builtin_amdgcn_mfma_f32_16x16x32_bf16(al, wh[ot], acc[mt][ot], 0, 0, 0);
                }
            }
        }
    }

    if (MODE == 0) {
#pragma unroll
        for (int mt = 0; mt < 8; mt++)
#pragma unroll
            for (int ot = 0; ot < 2; ot++) {
                int o = wv * 32 + ot * 16 + lc;
                float bs = bias[o];
#pragma unroll
                for (int r = 0; r < 4; r++) {
                    int n = n0 + mt * 16 + lg * 4 + r;
                    float v = acc[mt][ot][r] + bs;
                    unsigned short h = bf16_rne(v);
                    size_t idx = ((size_t)b * 4096 + n) * 128 + o;
                    outH[idx] = h;
                    outL[idx] = bf16_rne(v - bf16_to_f32(h));
                }
            }
    } else {
        const int mbase = blockIdx.x * 32;
#pragma unroll
        for (int mt = 0; mt < 4; mt++)
#pragma unroll
            for (int ot = 0; ot < 2; ot++) {
                int o = wv * 32 + ot * 16 + lc;
                float bs = bias[o];
#pragma unroll
                for (int pair = 0; pair < 2; pair++) {
                    float v = fmaxf(fmaxf(acc[mt][ot][2 * pair], acc[mt][ot][2 * pair + 1]),
                                    fmaxf(acc[mt + 4][ot][2 * pair], acc[mt + 4][ot][2 * pair + 1])) + bs;
                    int pw = mt * 8 + lg * 2 + pair;
                    int m  = mbase + pw;
                    if (MODE == 1) {
                        unsigned short h = bf16_rne(v);
                        size_t idx = ((size_t)b * 1024 + m) * 128 + o;
                        outH[idx] = h;
                        outL[idx] = bf16_rne(v - bf16_to_f32(h));
                    } else {
                        outH[((size_t)b * 128 + o) * 1024 + m] = bf16_rne(v);
                    }
                }
            }
    }
}

// ---------------------------------------------------------------------------
// Flash-style attention: block = 64 Q rows (4 waves x 16 rows), batch b.
// 16 K-tiles of 64 positions. K (hi+lo) staged in padded LDS shared by all
// waves, reg-prefetched one tile ahead (T14). Online softmax in registers.
// P -> per-wave private LDS buffer; PV reads V direct from L2.
// ---------------------------------------------------------------------------
__global__ __launch_bounds__(256, 3) void attn_kernel(
    const unsigned short* __restrict__ thH,  // [16][4096][128]
    const unsigned short* __restrict__ thL,
    const unsigned short* __restrict__ phH,  // [16][1024][128]
    const unsigned short* __restrict__ phL,
    const unsigned short* __restrict__ gp,   // [16][128][1024]  (V^T)
    unsigned short* __restrict__ y)          // [16][4096][128]
{
    const int b   = blockIdx.y;
    const int n0  = blockIdx.x * 64;
    const int tid = threadIdx.x;
    const int wv  = tid >> 6;
    const int l   = tid & 63;
    const int lg  = l >> 4;
    const int lc  = l & 15;

    // K tile: 64 rows x (128 + 8 pad) shorts  -> 17408 B each
    __shared__ __align__(16) unsigned short Kh[64 * 136];
    __shared__ __align__(16) unsigned short Kl[64 * 136];
    // P: per-wave private 16 x (64 + 8 pad)
    __shared__ __align__(16) unsigned short Pb[4][16 * 72];

    // ---- Q fragments (rows n0 + wv*16 + lc) ----
    s16x8 qh[4], ql[4];
    {
        const size_t qrow = ((size_t)b * 4096 + n0 + wv * 16 + lc) * 128;
#pragma unroll
        for (int ks = 0; ks < 4; ks++) {
            qh[ks] = *(const s16x8*)(thH + qrow + ks * 32 + lg * 8);
            ql[ks] = *(const s16x8*)(thL + qrow + ks * 32 + lg * 8);
        }
    }

    const unsigned short* phHb = phH + (size_t)b * 1024 * 128;
    const unsigned short* phLb = phL + (size_t)b * 1024 * 128;
    const unsigned short* gpb  = gp  + (size_t)b * 128 * 1024;

    // ---- prefetch K tile 0 into registers ----
    uint4 pf_h[4], pf_l[4];
#pragma unroll
    for (int i = 0; i < 4; i++) {
        int j = i * 256 + tid;
        int m = j >> 4, inner = j & 15;
        pf_h[i] = *(const uint4*)(phHb + (size_t)m * 128 + inner * 8);
        pf_l[i] = *(const uint4*)(phLb + (size_t)m * 128 + inner * 8);
    }

    f32x4 O[8];
#pragma unroll
    for (int t = 0; t < 8; t++) O[t] = (f32x4){0.f, 0.f, 0.f, 0.f};
    float mrun[4] = {-1e30f, -1e30f, -1e30f, -1e30f};
    float lrun[4] = {0.f, 0.f, 0.f, 0.f};

    unsigned short* Pw = Pb[wv];

    for (int kt = 0; kt < 16; kt++) {
        __syncthreads();   // prior tile's K reads complete
#pragma unroll
        for (int i = 0; i < 4; i++) {
            int j = i * 256 + tid;
            int m = j >> 4, inner = j & 15;
            *(uint4*)&Kh[m * 136 + inner * 8] = pf_h[i];
            *(uint4*)&Kl[m * 136 + inner * 8] = pf_l[i];
        }
        __syncthreads();   // K tile visible

        if (kt < 15) {
            const unsigned short* pn_h = phHb + (size_t)(kt + 1) * 64 * 128;
            const unsigned short* pn_l = phLb + (size_t)(kt + 1) * 64 * 128;
#pragma unroll
            for (int i = 0; i < 4; i++) {
                int j = i * 256 + tid;
                int m = j >> 4, inner = j & 15;
                pf_h[i] = *(const uint4*)(pn_h + (size_t)m * 128 + inner * 8);
                pf_l[i] = *(const uint4*)(pn_l + (size_t)m * 128 + inner * 8);
            }
        }

        // ---- QK^T for this tile: S = 16 rows x 64 cols ----
        f32x4 s[4];
#pragma unroll
        for (int ct = 0; ct < 4; ct++) s[ct] = (f32x4){0.f, 0.f, 0.f, 0.f};
#pragma unroll
        for (int ct = 0; ct < 4; ct++) {
#pragma unroll
            for (int ks = 0; ks < 4; ks++) {
                s16x8 kh = *(const s16x8*)&Kh[(ct * 16 + lc) * 136 + ks * 32 + lg * 8];
                s16x8 kl = *(const s16x8*)&Kl[(ct * 16 + lc) * 136 + ks * 32 + lg * 8];
                s[ct] = __builtin_amdgcn_mfma_f32_16x16x32_bf16(qh[ks], kh, s[ct], 0, 0, 0);
                s[ct] = __builtin_amdgcn_mfma_f32_16x16x32_bf16(qh[ks], kl, s[ct], 0, 0, 0);
                s[ct] = __builtin_amdgcn_mfma_f32_16x16x32_bf16(ql[ks], kh, s[ct], 0, 0, 0);
            }
        }

        // ---- online softmax update (rows = lg*4 + r) ----
        float tm[4];
#pragma unroll
        for (int r = 0; r < 4; r++)
            tm[r] = fmaxf(fmaxf(s[0][r], s[1][r]), fmaxf(s[2][r], s[3][r]));
#pragma unroll
        for (int d = 1; d < 16; d <<= 1)
#pragma unroll
            for (int r = 0; r < 4; r++) tm[r] = fmaxf(tm[r], __shfl_xor(tm[r], d, 64));

        float sc[4];
#pragma unroll
        for (int r = 0; r < 4; r++) {
            float mn = fmaxf(mrun[r], tm[r]);
            sc[r] = __expf(mrun[r] - mn);
            mrun[r] = mn;
        }
        float ts[4] = {0.f, 0.f, 0.f, 0.f};
#pragma unroll
        for (int ct = 0; ct < 4; ct++)
#pragma unroll
            for (int r = 0; r < 4; r++) {
                float e = __expf(s[ct][r] - mrun[r]);
                s[ct][r] = e;
                ts[r] += e;
            }
#pragma unroll
        for (int d = 1; d < 16; d <<= 1)
#pragma unroll
            for (int r = 0; r < 4; r++) ts[r] += __shfl_xor(ts[r], d, 64);
#pragma unroll
        for (int r = 0; r < 4; r++) lrun[r] = lrun[r] * sc[r] + ts[r];
#pragma unroll
        for (int t = 0; t < 8; t++)
#pragma unroll
            for (int r = 0; r < 4; r++) O[t][r] *= sc[r];

        // ---- P -> per-wave LDS ----
#pragma unroll
        for (int ct = 0; ct < 4; ct++)
#pragma unroll
            for (int r = 0; r < 4; r++)
                Pw[(lg * 4 + r) * 72 + ct * 16 + lc] = bf16_rne(s[ct][r]);

        // ---- PV: O += P (16x64) * V (64x128) ----
        const int mt = kt * 64;
#pragma unroll
        for (int kstep = 0; kstep < 2; kstep++) {
            s16x8 pa = *(const s16x8*)&Pw[lc * 72 + kstep * 32 + lg * 8];
#pragma unroll
            for (int ci_t = 0; ci_t < 8; ci_t++) {
                s16x8 vb = *(const s16x8*)(gpb + (size_t)(ci_t * 16 + lc) * 1024 + mt + kstep * 32 + lg * 8);
                O[ci_t] = __builtin_amdgcn_mfma_f32_16x16x32_bf16(pa, vb, O[ci_t], 0, 0, 0);
            }
        }
    }

    // ---- epilogue: normalize and store ----
#pragma unroll
    for (int r = 0; r < 4; r++) {
        float inv = 1.0f / lrun[r];
        int n = n0 + wv * 16 + lg * 4 + r;
        size_t base = ((size_t)b * 4096 + n) * 128;
#pragma unroll
        for (int ci_t = 0; ci_t < 8; ci_t++)
            y[base + ci_t * 16 + lc] = bf16_rne(O[ci_t][r] * inv);
    }
}

// ---------------------------------------------------------------------------
// W conv: W_y[b][o][n] = sum_ci W_w[o][ci] * y[b][n][ci] + W_b[o]   (bf16 out)
// ---------------------------------------------------------------------------
__global__ __launch_bounds__(256) void wconv_kernel(
    const unsigned short* __restrict__ y,   // [16][4096][128]
    const float* __restrict__ Ww,           // [256][128]
    const float* __restrict__ Wb,           // [256]
    unsigned short* __restrict__ wy)        // [16][256][4096]
{
    const int b   = blockIdx.z;
    const int o0  = blockIdx.x * 64;
    const int nb  = blockIdx.y * 256;
    const int tid = threadIdx.x;
    const int wv  = tid >> 6;
    const int l   = tid & 63;
    const int lg  = l >> 4;
    const int lc  = l & 15;
    const int n0  = nb + wv * 64;

    f32x4 acc[4][4];
#pragma unroll
    for (int i = 0; i < 4; i++)
#pragma unroll
        for (int j = 0; j < 4; j++) acc[i][j] = (f32x4){0.f, 0.f, 0.f, 0.f};

#pragma unroll
    for (int ks = 0; ks < 4; ks++) {
        s16x8 a[4];
#pragma unroll
        for (int ot = 0; ot < 4; ot++) {
            const float* wp = Ww + (size_t)(o0 + ot * 16 + lc) * 128 + ks * 32 + lg * 8;
#pragma unroll
            for (int j = 0; j < 8; j++) a[ot][j] = (short)bf16_rne(wp[j]);
        }
#pragma unroll
        for (int nt = 0; nt < 4; nt++) {
            s16x8 bf = *(const s16x8*)(y + ((size_t)b * 4096 + n0 + nt * 16 + lc) * 128 + ks * 32 + lg * 8);
#pragma unroll
            for (int ot = 0; ot < 4; ot++)
                acc[ot][nt] = __builtin_amdgcn_mfma_f32_16x16x32_bf16(a[ot], bf, acc[ot][nt], 0, 0, 0);
        }
    }
#pragma unroll
    for (int ot = 0; ot < 4; ot++) {
#pragma unroll
        for (int r = 0; r < 4; r++) {
            int o = o0 + ot * 16 + lg * 4 + r;
            float bsv = Wb[o];
#pragma unroll
            for (int nt = 0; nt < 4; nt++) {
                float v = acc[ot][nt][r] + bsv;
                wy[((size_t)b * 256 + o) * 4096 + n0 + nt * 16 + lc] = bf16_rne(v);
            }
        }
    }
}

// ---------------------------------------------------------------------------
__global__ __launch_bounds__(256) void stats_kernel(
    const unsigned short* __restrict__ wy,  // [16][256][4096]
    const float* __restrict__ gamma, const float* __restrict__ beta,
    float* __restrict__ scale, float* __restrict__ shift)
{
    const int o = blockIdx.x;
    const int t = threadIdx.x;
    float s1 = 0.f, s2 = 0.f;
    for (int b = 0; b < 16; b++) {
        const unsigned short* p = wy + ((size_t)b * 256 + o) * 4096;
#pragma unroll
        for (int i = 0; i < 4; i++) {
            uint2 u = *(const uint2*)(p + i * 1024 + t * 4);
            float v0 = bf16_to_f32((unsigned short)(u.x & 0xffff));
            float v1 = bf16_to_f32((unsigned short)(u.x >> 16));
            float v2 = bf16_to_f32((unsigned short)(u.y & 0xffff));
            float v3 = bf16_to_f32((unsigned short)(u.y >> 16));
            s1 += v0 + v1 + v2 + v3;
            s2 += v0 * v0 + v1 * v1 + v2 * v2 + v3 * v3;
        }
    }
#pragma unroll
    for (int d = 1; d < 64; d <<= 1) { s1 += __shfl_xor(s1, d, 64); s2 += __shfl_xor(s2, d, 64); }
    __shared__ float rs1[4], rs2[4];
    if ((t & 63) == 0) { rs1[t >> 6] = s1; rs2[t >> 6] = s2; }
    __syncthreads();
    if (t == 0) {
        float S1 = rs1[0] + rs1[1] + rs1[2] + rs1[3];
        float S2 = rs2[0] + rs2[1] + rs2[2] + rs2[3];
        const float cnt = 16.0f * 4096.0f;
        float mean = S1 / cnt;
        float var  = S2 / cnt - mean * mean;
        float sc = gamma[o] * rsqrtf(var + 1e-5f);
        scale[o] = sc;
        shift[o] = beta[o] - mean * sc;
    }
}

// ---------------------------------------------------------------------------
__global__ __launch_bounds__(256) void final_kernel(
    const unsigned short* __restrict__ wy,
    const float* __restrict__ x,
    const float* __restrict__ scale, const float* __restrict__ shift,
    const float* __restrict__ inp0,
    float* __restrict__ out)
{
    if (blockIdx.x == 0 && threadIdx.x == 0) out[0] = inp0[0];
    float* z = out + 1;
    const size_t total4 = (size_t)16 * 256 * 4096 / 4;
    for (size_t v = (size_t)blockIdx.x * 256 + threadIdx.x; v < total4; v += (size_t)gridDim.x * 256) {
        size_t e = v * 4;
        int c = (int)((e >> 12) & 255);
        uint2 u = *(const uint2*)(wy + e);
        float4 xv = *(const float4*)(x + e);
        float sc = scale[c], sh = shift[c];
        float z0 = sc * bf16_to_f32((unsigned short)(u.x & 0xffff)) + sh + xv.x;
        float z1 = sc * bf16_to_f32((unsigned short)(u.x >> 16))    + sh + xv.y;
        float z2 = sc * bf16_to_f32((unsigned short)(u.y & 0xffff)) + sh + xv.z;
        float z3 = sc * bf16_to_f32((unsigned short)(u.y >> 16))    + sh + xv.w;
        z[e + 0] = z0; z[e + 1] = z1; z[e + 2] = z2; z[e + 3] = z3;
    }
}

// ---------------------------------------------------------------------------
extern "C" void kernel_launch(void* const* d_in, const int* in_sizes, int n_in,
                              void* d_out, int out_size, void* d_ws, size_t ws_size,
                              hipStream_t stream) {
    const float* inp0  = (const float*)d_in[0];
    const float* x     = (const float*)d_in[1];
    const float* g_w   = (const float*)d_in[2];
    const float* g_b   = (const float*)d_in[3];
    const float* th_w  = (const float*)d_in[4];
    const float* th_b  = (const float*)d_in[5];
    const float* ph_w  = (const float*)d_in[6];
    const float* ph_b  = (const float*)d_in[7];
    const float* W_w   = (const float*)d_in[8];
    const float* W_b   = (const float*)d_in[9];
    const float* gamma = (const float*)d_in[10];
    const float* beta  = (const float*)d_in[11];

    char* ws = (char*)d_ws;
    const size_t MB = 1048576;
    unsigned short* thH = (unsigned short*)(ws);                  // 16 MB
    unsigned short* thL = (unsigned short*)(ws + 16 * MB);        // 16 MB
    unsigned short* phH = (unsigned short*)(ws + 32 * MB);        // 4 MB
    unsigned short* phL = (unsigned short*)(ws + 36 * MB);        // 4 MB
    unsigned short* gpv = (unsigned short*)(ws + 40 * MB);        // 4 MB
    unsigned short* yv  = (unsigned short*)(ws + 44 * MB);        // 16 MB
    unsigned short* wy  = (unsigned short*)(ws + 60 * MB);        // 32 MB
    float* scaleb       = (float*)(ws + 92 * MB);                 // 1 KB
    float* shiftb       = (float*)(ws + 92 * MB + 1024);          // 1 KB

    conv_kernel<0><<<dim3(32, 16), 256, 0, stream>>>(x, th_w, th_b, thH, thL);
    conv_kernel<1><<<dim3(32, 16), 256, 0, stream>>>(x, ph_w, ph_b, phH, phL);
    conv_kernel<2><<<dim3(32, 16), 256, 0, stream>>>(x, g_w, g_b, gpv, gpv);
    attn_kernel<<<dim3(64, 16), 256, 0, stream>>>(thH, thL, phH, phL, gpv, yv);
    wconv_kernel<<<dim3(4, 16, 16), 256, 0, stream>>>(yv, W_w, W_b, wy);
    stats_kernel<<<dim3(256), 256, 0, stream>>>(wy, gamma, beta, scaleb, shiftb);
    final_kernel<<<dim3(2048), 256, 0, stream>>>(wy, x, scaleb, shiftb, inp0, (float*)d_out);
}

// Round 3
// 424.202 us; speedup vs baseline: 1.4433x; 1.2856x over previous
//
#include <hip/hip_runtime.h>
#include <stdint.h>

typedef __attribute__((ext_vector_type(4))) float f32x4;
typedef __attribute__((ext_vector_type(8))) short s16x8;

// ---------- bf16 helpers ----------
__device__ __forceinline__ unsigned short bf16_rne(float f) {
    union { float f; unsigned u; } v; v.f = f;
    return (unsigned short)((v.u + 0x7fffu + ((v.u >> 16) & 1u)) >> 16);
}
__device__ __forceinline__ float bf16_to_f32(unsigned short h) {
    union { unsigned u; float f; } v; v.u = ((unsigned)h) << 16;
    return v.f;
}

// async global->LDS 16B per lane. LDS dest must be wave-uniform base (+lane*16).
__device__ __forceinline__ void async_copy16(unsigned short* lds, const unsigned short* glb) {
    __builtin_amdgcn_global_load_lds(
        (const __attribute__((address_space(1))) unsigned int*)(glb),
        (__attribute__((address_space(3))) unsigned int*)(lds),
        16, 0, 0);
}

// Problem dims: B=16, C=256, CI=128, H=W=64, N=4096, NP=1024 (pooled 32x32)

// ---------------------------------------------------------------------------
// conv1x1 kernel. MODE 0: theta (no pool, split hi/lo out [b][n][o])
//                 MODE 1: phi   (pool,  split hi/lo out [b][m][o])
//                 MODE 2: g     (pool,  single     out [b][o][m])
// ---------------------------------------------------------------------------
template<int MODE>
__global__ __launch_bounds__(256) void conv_kernel(
    const float* __restrict__ x,      // [16][256][4096]
    const float* __restrict__ w,      // [128][256]
    const float* __restrict__ bias,   // [128]
    unsigned short* __restrict__ outH,
    unsigned short* __restrict__ outL)
{
    const int b   = blockIdx.y;
    const int n0  = blockIdx.x * 128;
    const int tid = threadIdx.x;
    const int wv  = tid >> 6;
    const int l   = tid & 63;
    const int lg  = l >> 4;   // lane group 0..3
    const int lc  = l & 15;   // lane col  0..15

    __shared__ __align__(16) unsigned short Ah[128][40];
    __shared__ __align__(16) unsigned short Al[128][40];

    f32x4 acc[8][2];
#pragma unroll
    for (int i = 0; i < 8; i++)
#pragma unroll
        for (int j = 0; j < 2; j++) acc[i][j] = (f32x4){0.f, 0.f, 0.f, 0.f};

    for (int kc = 0; kc < 256; kc += 32) {
        __syncthreads();
#pragma unroll
        for (int i = 0; i < 16; i++) {
            int lin = i * 256 + tid;     // 0..4095
            int cc  = lin >> 7;          // 0..31
            int nn  = lin & 127;
            float v = x[((size_t)b * 256 + (kc + cc)) * 4096 + n0 + nn];
            unsigned short h = bf16_rne(v);
            Ah[nn][cc] = h;
            if (MODE != 2) Al[nn][cc] = bf16_rne(v - bf16_to_f32(h));
        }
        __syncthreads();

        s16x8 wh[2], wl[2];
#pragma unroll
        for (int ot = 0; ot < 2; ot++) {
            int orow = wv * 32 + ot * 16 + lc;
            const float* wp = w + (size_t)orow * 256 + kc + lg * 8;
#pragma unroll
            for (int j = 0; j < 8; j++) {
                float wvv = wp[j];
                unsigned short h = bf16_rne(wvv);
                wh[ot][j] = (short)h;
                if (MODE != 2) wl[ot][j] = (short)bf16_rne(wvv - bf16_to_f32(h));
            }
        }

#pragma unroll
        for (int mt = 0; mt < 8; mt++) {
            s16x8 ah = *(const s16x8*)&Ah[mt * 16 + lc][lg * 8];
            s16x8 al;
            if (MODE != 2) al = *(const s16x8*)&Al[mt * 16 + lc][lg * 8];
#pragma unroll
            for (int ot = 0; ot < 2; ot++) {
                acc[mt][ot] = __builtin_amdgcn_mfma_f32_16x16x32_bf16(ah, wh[ot], acc[mt][ot], 0, 0, 0);
                if (MODE != 2) {
                    acc[mt][ot] = __builtin_amdgcn_mfma_f32_16x16x32_bf16(ah, wl[ot], acc[mt][ot], 0, 0, 0);
                    acc[mt][ot] = __builtin_amdgcn_mfma_f32_16x16x32_bf16(al, wh[ot], acc[mt][ot], 0, 0, 0);
                }
            }
        }
    }

    if (MODE == 0) {
#pragma unroll
        for (int mt = 0; mt < 8; mt++)
#pragma unroll
            for (int ot = 0; ot < 2; ot++) {
                int o = wv * 32 + ot * 16 + lc;
                float bs = bias[o];
#pragma unroll
                for (int r = 0; r < 4; r++) {
                    int n = n0 + mt * 16 + lg * 4 + r;
                    float v = acc[mt][ot][r] + bs;
                    unsigned short h = bf16_rne(v);
                    size_t idx = ((size_t)b * 4096 + n) * 128 + o;
                    outH[idx] = h;
                    outL[idx] = bf16_rne(v - bf16_to_f32(h));
                }
            }
    } else {
        const int mbase = blockIdx.x * 32;
#pragma unroll
        for (int mt = 0; mt < 4; mt++)
#pragma unroll
            for (int ot = 0; ot < 2; ot++) {
                int o = wv * 32 + ot * 16 + lc;
                float bs = bias[o];
#pragma unroll
                for (int pair = 0; pair < 2; pair++) {
                    float v = fmaxf(fmaxf(acc[mt][ot][2 * pair], acc[mt][ot][2 * pair + 1]),
                                    fmaxf(acc[mt + 4][ot][2 * pair], acc[mt + 4][ot][2 * pair + 1])) + bs;
                    int pw = mt * 8 + lg * 2 + pair;
                    int m  = mbase + pw;
                    if (MODE == 1) {
                        unsigned short h = bf16_rne(v);
                        size_t idx = ((size_t)b * 1024 + m) * 128 + o;
                        outH[idx] = h;
                        outL[idx] = bf16_rne(v - bf16_to_f32(h));
                    } else {
                        outH[((size_t)b * 128 + o) * 1024 + m] = bf16_rne(v);
                    }
                }
            }
    }
}

// ---------------------------------------------------------------------------
// Flash attention v3: block = 128 Q rows (4 waves x 32 rows = 2 row-tiles),
// grid 32 x 16 = 512 blocks = exactly 2/CU. K (hi+lo) double-buffered in
// XOR-swizzled LDS via global_load_lds (async, zero VGPR staging). Each K
// fragment read feeds 6 MFMAs (2 row-tiles x 3 split terms). Online softmax
// in registers. P (both row-tiles) in swizzled LDS; V read once per kt from L2.
// ---------------------------------------------------------------------------
__global__ __launch_bounds__(256, 2) void attn_kernel(
    const unsigned short* __restrict__ thH,  // [16][4096][128]
    const unsigned short* __restrict__ thL,
    const unsigned short* __restrict__ phH,  // [16][1024][128]
    const unsigned short* __restrict__ phL,
    const unsigned short* __restrict__ gp,   // [16][128][1024]  (V^T)
    unsigned short* __restrict__ y)          // [16][4096][128]
{
    const int b   = blockIdx.y;
    const int n0  = blockIdx.x * 128;
    const int tid = threadIdx.x;
    const int wv  = tid >> 6;
    const int l   = tid & 63;
    const int lg  = l >> 4;
    const int lc  = l & 15;

    // K tile buffers: [2][64 rows][16 chunks of 8 shorts], chunk slot = chunk ^ (row&15)
    __shared__ __align__(16) unsigned short Kh[2][64 * 128];
    __shared__ __align__(16) unsigned short Kl[2][64 * 128];
    // P: per-wave [32 rows][8 chunks of 8 shorts], slot = chunk ^ (row&7)
    __shared__ __align__(16) unsigned short Pb[4][32 * 64];

    const unsigned short* phHb = phH + (size_t)b * 1024 * 128;
    const unsigned short* phLb = phL + (size_t)b * 1024 * 128;
    const unsigned short* gpb  = gp  + (size_t)b * 128 * 1024;
    unsigned short* Pw = Pb[wv];

    // ---- Q fragments: rows n0 + wv*32 + rt*16 + lc ----
    s16x8 qh[2][4], ql[2][4];
#pragma unroll
    for (int rt = 0; rt < 2; rt++) {
        const size_t qrow = ((size_t)b * 4096 + n0 + wv * 32 + rt * 16 + lc) * 128;
#pragma unroll
        for (int ks = 0; ks < 4; ks++) {
            qh[rt][ks] = *(const s16x8*)(thH + qrow + ks * 32 + lg * 8);
            ql[rt][ks] = *(const s16x8*)(thL + qrow + ks * 32 + lg * 8);
        }
    }

    f32x4 O[2][8];
#pragma unroll
    for (int rt = 0; rt < 2; rt++)
#pragma unroll
        for (int t = 0; t < 8; t++) O[rt][t] = (f32x4){0.f, 0.f, 0.f, 0.f};
    float mrun[2][4], lrun[2][4];
#pragma unroll
    for (int rt = 0; rt < 2; rt++)
#pragma unroll
        for (int r = 0; r < 4; r++) { mrun[rt][r] = -1e30f; lrun[rt][r] = 0.f; }

    // stage: wave wv stages rows [wv*16, wv*16+16) of tile kt into buffer buf.
    // lane l handles row Rt+(l>>4), slot (l&15); global chunk = slot ^ (R&15).
    const int lr = l >> 4;
    const int sc_ = l & 15;
#define STAGE(buf, kt_)                                                              \
    {                                                                                \
        _Pragma("unroll")                                                            \
        for (int t = 0; t < 4; t++) {                                                \
            int Rt = wv * 16 + t * 4;                                                \
            int R  = Rt + lr;                                                        \
            int ck = sc_ ^ (R & 15);                                                 \
            const unsigned short* sH = phHb + ((size_t)((kt_) * 64 + R)) * 128 + ck * 8; \
            const unsigned short* sL = phLb + ((size_t)((kt_) * 64 + R)) * 128 + ck * 8; \
            async_copy16(&Kh[buf][Rt * 128], sH);                                    \
            async_copy16(&Kl[buf][Rt * 128], sL);                                    \
        }                                                                            \
    }

    STAGE(0, 0);

    for (int kt = 0; kt < 16; kt++) {
        const int cur = kt & 1;
        __syncthreads();                 // drains vmcnt -> tile kt visible to all
        if (kt < 15) STAGE(cur ^ 1, kt + 1);

        const unsigned short* KhT = Kh[cur];
        const unsigned short* KlT = Kl[cur];

        // ---- QK^T: 2 row-tiles x 64 cols, split-bf16 (hh+hl+lh) ----
        f32x4 s[2][4];
#pragma unroll
        for (int rt = 0; rt < 2; rt++)
#pragma unroll
            for (int ct = 0; ct < 4; ct++) s[rt][ct] = (f32x4){0.f, 0.f, 0.f, 0.f};

#pragma unroll
        for (int ct = 0; ct < 4; ct++) {
            const int row = ct * 16 + lc;
#pragma unroll
            for (int ks = 0; ks < 4; ks++) {
                const int slot = (ks * 4 + lg) ^ lc;
                s16x8 kh = *(const s16x8*)(KhT + row * 128 + slot * 8);
                s16x8 kl = *(const s16x8*)(KlT + row * 128 + slot * 8);
                s[0][ct] = __builtin_amdgcn_mfma_f32_16x16x32_bf16(qh[0][ks], kh, s[0][ct], 0, 0, 0);
                s[0][ct] = __builtin_amdgcn_mfma_f32_16x16x32_bf16(qh[0][ks], kl, s[0][ct], 0, 0, 0);
                s[0][ct] = __builtin_amdgcn_mfma_f32_16x16x32_bf16(ql[0][ks], kh, s[0][ct], 0, 0, 0);
                s[1][ct] = __builtin_amdgcn_mfma_f32_16x16x32_bf16(qh[1][ks], kh, s[1][ct], 0, 0, 0);
                s[1][ct] = __builtin_amdgcn_mfma_f32_16x16x32_bf16(qh[1][ks], kl, s[1][ct], 0, 0, 0);
                s[1][ct] = __builtin_amdgcn_mfma_f32_16x16x32_bf16(ql[1][ks], kh, s[1][ct], 0, 0, 0);
            }
        }

        // ---- online softmax per row-tile (rows = rt*16 + lg*4 + r) ----
#pragma unroll
        for (int rt = 0; rt < 2; rt++) {
            float tm[4];
#pragma unroll
            for (int r = 0; r < 4; r++)
                tm[r] = fmaxf(fmaxf(s[rt][0][r], s[rt][1][r]), fmaxf(s[rt][2][r], s[rt][3][r]));
#pragma unroll
            for (int d = 1; d < 16; d <<= 1)
#pragma unroll
                for (int r = 0; r < 4; r++) tm[r] = fmaxf(tm[r], __shfl_xor(tm[r], d, 64));

            float scv[4];
#pragma unroll
            for (int r = 0; r < 4; r++) {
                float mn = fmaxf(mrun[rt][r], tm[r]);
                scv[r] = __expf(mrun[rt][r] - mn);
                mrun[rt][r] = mn;
            }
            float ts[4] = {0.f, 0.f, 0.f, 0.f};
#pragma unroll
            for (int ct = 0; ct < 4; ct++)
#pragma unroll
                for (int r = 0; r < 4; r++) {
                    float e = __expf(s[rt][ct][r] - mrun[rt][r]);
                    s[rt][ct][r] = e;
                    ts[r] += e;
                }
#pragma unroll
            for (int d = 1; d < 16; d <<= 1)
#pragma unroll
                for (int r = 0; r < 4; r++) ts[r] += __shfl_xor(ts[r], d, 64);
#pragma unroll
            for (int r = 0; r < 4; r++) lrun[rt][r] = lrun[rt][r] * scv[r] + ts[r];
#pragma unroll
            for (int t = 0; t < 8; t++)
#pragma unroll
                for (int r = 0; r < 4; r++) O[rt][t][r] *= scv[r];

            // P -> swizzled LDS: row = rt*16+lg*4+r, col = ct*16+lc
#pragma unroll
            for (int ct = 0; ct < 4; ct++)
#pragma unroll
                for (int r = 0; r < 4; r++) {
                    int row = rt * 16 + lg * 4 + r;
                    int cch = ct * 2 + (lc >> 3);
                    Pw[row * 64 + ((cch ^ (row & 7)) << 3) + (lc & 7)] = bf16_rne(s[rt][ct][r]);
                }
        }

        // ---- PV: O += P(32x64) * V(64x128), V read once ----
        const int mt = kt * 64;
#pragma unroll
        for (int kstep = 0; kstep < 2; kstep++) {
            const int pch = kstep * 4 + lg;
            s16x8 pa0 = *(const s16x8*)(Pw + (lc) * 64 + ((pch ^ (lc & 7)) << 3));
            s16x8 pa1 = *(const s16x8*)(Pw + (16 + lc) * 64 + ((pch ^ (lc & 7)) << 3));
#pragma unroll
            for (int ci_t = 0; ci_t < 8; ci_t++) {
                s16x8 vb = *(const s16x8*)(gpb + (size_t)(ci_t * 16 + lc) * 1024 + mt + kstep * 32 + lg * 8);
                O[0][ci_t] = __builtin_amdgcn_mfma_f32_16x16x32_bf16(pa0, vb, O[0][ci_t], 0, 0, 0);
                O[1][ci_t] = __builtin_amdgcn_mfma_f32_16x16x32_bf16(pa1, vb, O[1][ci_t], 0, 0, 0);
            }
        }
    }

    // ---- epilogue: normalize and store ----
#pragma unroll
    for (int rt = 0; rt < 2; rt++)
#pragma unroll
        for (int r = 0; r < 4; r++) {
            float inv = 1.0f / lrun[rt][r];
            int n = n0 + wv * 32 + rt * 16 + lg * 4 + r;
            size_t base = ((size_t)b * 4096 + n) * 128;
#pragma unroll
            for (int ci_t = 0; ci_t < 8; ci_t++)
                y[base + ci_t * 16 + lc] = bf16_rne(O[rt][ci_t][r] * inv);
        }
#undef STAGE
}

// ---------------------------------------------------------------------------
// W conv: W_y[b][o][n] = sum_ci W_w[o][ci] * y[b][n][ci] + W_b[o]   (bf16 out)
// ---------------------------------------------------------------------------
__global__ __launch_bounds__(256) void wconv_kernel(
    const unsigned short* __restrict__ y,   // [16][4096][128]
    const float* __restrict__ Ww,           // [256][128]
    const float* __restrict__ Wb,           // [256]
    unsigned short* __restrict__ wy)        // [16][256][4096]
{
    const int b   = blockIdx.z;
    const int o0  = blockIdx.x * 64;
    const int nb  = blockIdx.y * 256;
    const int tid = threadIdx.x;
    const int wv  = tid >> 6;
    const int l   = tid & 63;
    const int lg  = l >> 4;
    const int lc  = l & 15;
    const int n0  = nb + wv * 64;

    f32x4 acc[4][4];
#pragma unroll
    for (int i = 0; i < 4; i++)
#pragma unroll
        for (int j = 0; j < 4; j++) acc[i][j] = (f32x4){0.f, 0.f, 0.f, 0.f};

#pragma unroll
    for (int ks = 0; ks < 4; ks++) {
        s16x8 a[4];
#pragma unroll
        for (int ot = 0; ot < 4; ot++) {
            const float* wp = Ww + (size_t)(o0 + ot * 16 + lc) * 128 + ks * 32 + lg * 8;
#pragma unroll
            for (int j = 0; j < 8; j++) a[ot][j] = (short)bf16_rne(wp[j]);
        }
#pragma unroll
        for (int nt = 0; nt < 4; nt++) {
            s16x8 bf = *(const s16x8*)(y + ((size_t)b * 4096 + n0 + nt * 16 + lc) * 128 + ks * 32 + lg * 8);
#pragma unroll
            for (int ot = 0; ot < 4; ot++)
                acc[ot][nt] = __builtin_amdgcn_mfma_f32_16x16x32_bf16(a[ot], bf, acc[ot][nt], 0, 0, 0);
        }
    }
#pragma unroll
    for (int ot = 0; ot < 4; ot++) {
#pragma unroll
        for (int r = 0; r < 4; r++) {
            int o = o0 + ot * 16 + lg * 4 + r;
            float bsv = Wb[o];
#pragma unroll
            for (int nt = 0; nt < 4; nt++) {
                float v = acc[ot][nt][r] + bsv;
                wy[((size_t)b * 256 + o) * 4096 + n0 + nt * 16 + lc] = bf16_rne(v);
            }
        }
    }
}

// ---------------------------------------------------------------------------
__global__ __launch_bounds__(256) void stats_kernel(
    const unsigned short* __restrict__ wy,  // [16][256][4096]
    const float* __restrict__ gamma, const float* __restrict__ beta,
    float* __restrict__ scale, float* __restrict__ shift)
{
    const int o = blockIdx.x;
    const int t = threadIdx.x;
    float s1 = 0.f, s2 = 0.f;
    for (int b = 0; b < 16; b++) {
        const unsigned short* p = wy + ((size_t)b * 256 + o) * 4096;
#pragma unroll
        for (int i = 0; i < 4; i++) {
            uint2 u = *(const uint2*)(p + i * 1024 + t * 4);
            float v0 = bf16_to_f32((unsigned short)(u.x & 0xffff));
            float v1 = bf16_to_f32((unsigned short)(u.x >> 16));
            float v2 = bf16_to_f32((unsigned short)(u.y & 0xffff));
            float v3 = bf16_to_f32((unsigned short)(u.y >> 16));
            s1 += v0 + v1 + v2 + v3;
            s2 += v0 * v0 + v1 * v1 + v2 * v2 + v3 * v3;
        }
    }
#pragma unroll
    for (int d = 1; d < 64; d <<= 1) { s1 += __shfl_xor(s1, d, 64); s2 += __shfl_xor(s2, d, 64); }
    __shared__ float rs1[4], rs2[4];
    if ((t & 63) == 0) { rs1[t >> 6] = s1; rs2[t >> 6] = s2; }
    __syncthreads();
    if (t == 0) {
        float S1 = rs1[0] + rs1[1] + rs1[2] + rs1[3];
        float S2 = rs2[0] + rs2[1] + rs2[2] + rs2[3];
        const float cnt = 16.0f * 4096.0f;
        float mean = S1 / cnt;
        float var  = S2 / cnt - mean * mean;
        float sc = gamma[o] * rsqrtf(var + 1e-5f);
        scale[o] = sc;
        shift[o] = beta[o] - mean * sc;
    }
}

// ---------------------------------------------------------------------------
__global__ __launch_bounds__(256) void final_kernel(
    const unsigned short* __restrict__ wy,
    const float* __restrict__ x,
    const float* __restrict__ scale, const float* __restrict__ shift,
    const float* __restrict__ inp0,
    float* __restrict__ out)
{
    if (blockIdx.x == 0 && threadIdx.x == 0) out[0] = inp0[0];
    float* z = out + 1;
    const size_t total4 = (size_t)16 * 256 * 4096 / 4;
    for (size_t v = (size_t)blockIdx.x * 256 + threadIdx.x; v < total4; v += (size_t)gridDim.x * 256) {
        size_t e = v * 4;
        int c = (int)((e >> 12) & 255);
        uint2 u = *(const uint2*)(wy + e);
        float4 xv = *(const float4*)(x + e);
        float sc = scale[c], sh = shift[c];
        float z0 = sc * bf16_to_f32((unsigned short)(u.x & 0xffff)) + sh + xv.x;
        float z1 = sc * bf16_to_f32((unsigned short)(u.x >> 16))    + sh + xv.y;
        float z2 = sc * bf16_to_f32((unsigned short)(u.y & 0xffff)) + sh + xv.z;
        float z3 = sc * bf16_to_f32((unsigned short)(u.y >> 16))    + sh + xv.w;
        z[e + 0] = z0; z[e + 1] = z1; z[e + 2] = z2; z[e + 3] = z3;
    }
}

// ---------------------------------------------------------------------------
extern "C" void kernel_launch(void* const* d_in, const int* in_sizes, int n_in,
                              void* d_out, int out_size, void* d_ws, size_t ws_size,
                              hipStream_t stream) {
    const float* inp0  = (const float*)d_in[0];
    const float* x     = (const float*)d_in[1];
    const float* g_w   = (const float*)d_in[2];
    const float* g_b   = (const float*)d_in[3];
    const float* th_w  = (const float*)d_in[4];
    const float* th_b  = (const float*)d_in[5];
    const float* ph_w  = (const float*)d_in[6];
    const float* ph_b  = (const float*)d_in[7];
    const float* W_w   = (const float*)d_in[8];
    const float* W_b   = (const float*)d_in[9];
    const float* gamma = (const float*)d_in[10];
    const float* beta  = (const float*)d_in[11];

    char* ws = (char*)d_ws;
    const size_t MB = 1048576;
    unsigned short* thH = (unsigned short*)(ws);                  // 16 MB
    unsigned short* thL = (unsigned short*)(ws + 16 * MB);        // 16 MB
    unsigned short* phH = (unsigned short*)(ws + 32 * MB);        // 4 MB
    unsigned short* phL = (unsigned short*)(ws + 36 * MB);        // 4 MB
    unsigned short* gpv = (unsigned short*)(ws + 40 * MB);        // 4 MB
    unsigned short* yv  = (unsigned short*)(ws + 44 * MB);        // 16 MB
    unsigned short* wy  = (unsigned short*)(ws + 60 * MB);        // 32 MB
    float* scaleb       = (float*)(ws + 92 * MB);                 // 1 KB
    float* shiftb       = (float*)(ws + 92 * MB + 1024);          // 1 KB

    conv_kernel<0><<<dim3(32, 16), 256, 0, stream>>>(x, th_w, th_b, thH, thL);
    conv_kernel<1><<<dim3(32, 16), 256, 0, stream>>>(x, ph_w, ph_b, phH, phL);
    conv_kernel<2><<<dim3(32, 16), 256, 0, stream>>>(x, g_w, g_b, gpv, gpv);
    attn_kernel<<<dim3(32, 16), 256, 0, stream>>>(thH, thL, phH, phL, gpv, yv);
    wconv_kernel<<<dim3(4, 16, 16), 256, 0, stream>>>(yv, W_w, W_b, wy);
    stats_kernel<<<dim3(256), 256, 0, stream>>>(wy, gamma, beta, scaleb, shiftb);
    final_kernel<<<dim3(2048), 256, 0, stream>>>(wy, x, scaleb, shiftb, inp0, (float*)d_out);
}

// Round 7
// 418.809 us; speedup vs baseline: 1.4619x; 1.0129x over previous
//
#include <hip/hip_runtime.h>
#include <stdint.h>

typedef __attribute__((ext_vector_type(4))) float f32x4;
typedef __attribute__((ext_vector_type(8))) short s16x8;

// ---------- bf16 helpers ----------
__device__ __forceinline__ unsigned short bf16_rne(float f) {
    union { float f; unsigned u; } v; v.f = f;
    return (unsigned short)((v.u + 0x7fffu + ((v.u >> 16) & 1u)) >> 16);
}
__device__ __forceinline__ float bf16_to_f32(unsigned short h) {
    union { unsigned u; float f; } v; v.u = ((unsigned)h) << 16;
    return v.f;
}

// async global->LDS 16B per lane. LDS dest must be wave-uniform base (+lane*16).
__device__ __forceinline__ void async_copy16(unsigned short* lds, const unsigned short* glb) {
    __builtin_amdgcn_global_load_lds(
        (const __attribute__((address_space(1))) unsigned int*)(glb),
        (__attribute__((address_space(3))) unsigned int*)(lds),
        16, 0, 0);
}

// Problem dims: B=16, C=256, CI=128, H=W=64, N=4096, NP=1024 (pooled 32x32)

// ---------------------------------------------------------------------------
// conv1x1 kernel. MODE 0: theta (no pool, split hi/lo out [b][n][o])
//                 MODE 1: phi   (pool,  split hi/lo out [b][m][o])
//                 MODE 2: g     (pool,  single     out [b][o][m])
// ---------------------------------------------------------------------------
template<int MODE>
__global__ __launch_bounds__(256) void conv_kernel(
    const float* __restrict__ x,      // [16][256][4096]
    const float* __restrict__ w,      // [128][256]
    const float* __restrict__ bias,   // [128]
    unsigned short* __restrict__ outH,
    unsigned short* __restrict__ outL)
{
    const int b   = blockIdx.y;
    const int n0  = blockIdx.x * 128;
    const int tid = threadIdx.x;
    const int wv  = tid >> 6;
    const int l   = tid & 63;
    const int lg  = l >> 4;   // lane group 0..3
    const int lc  = l & 15;   // lane col  0..15

    __shared__ __align__(16) unsigned short Ah[128][40];
    __shared__ __align__(16) unsigned short Al[128][40];

    f32x4 acc[8][2];
#pragma unroll
    for (int i = 0; i < 8; i++)
#pragma unroll
        for (int j = 0; j < 2; j++) acc[i][j] = (f32x4){0.f, 0.f, 0.f, 0.f};

    for (int kc = 0; kc < 256; kc += 32) {
        __syncthreads();
#pragma unroll
        for (int i = 0; i < 16; i++) {
            int lin = i * 256 + tid;     // 0..4095
            int cc  = lin >> 7;          // 0..31
            int nn  = lin & 127;
            float v = x[((size_t)b * 256 + (kc + cc)) * 4096 + n0 + nn];
            unsigned short h = bf16_rne(v);
            Ah[nn][cc] = h;
            if (MODE != 2) Al[nn][cc] = bf16_rne(v - bf16_to_f32(h));
        }
        __syncthreads();

        s16x8 wh[2], wl[2];
#pragma unroll
        for (int ot = 0; ot < 2; ot++) {
            int orow = wv * 32 + ot * 16 + lc;
            const float* wp = w + (size_t)orow * 256 + kc + lg * 8;
#pragma unroll
            for (int j = 0; j < 8; j++) {
                float wvv = wp[j];
                unsigned short h = bf16_rne(wvv);
                wh[ot][j] = (short)h;
                if (MODE != 2) wl[ot][j] = (short)bf16_rne(wvv - bf16_to_f32(h));
            }
        }

#pragma unroll
        for (int mt = 0; mt < 8; mt++) {
            s16x8 ah = *(const s16x8*)&Ah[mt * 16 + lc][lg * 8];
            s16x8 al;
            if (MODE != 2) al = *(const s16x8*)&Al[mt * 16 + lc][lg * 8];
#pragma unroll
            for (int ot = 0; ot < 2; ot++) {
                acc[mt][ot] = __builtin_amdgcn_mfma_f32_16x16x32_bf16(ah, wh[ot], acc[mt][ot], 0, 0, 0);
                if (MODE != 2) {
                    acc[mt][ot] = __builtin_amdgcn_mfma_f32_16x16x32_bf16(ah, wl[ot], acc[mt][ot], 0, 0, 0);
                    acc[mt][ot] = __builtin_amdgcn_mfma_f32_16x16x32_bf16(al, wh[ot], acc[mt][ot], 0, 0, 0);
                }
            }
        }
    }

    if (MODE == 0) {
#pragma unroll
        for (int mt = 0; mt < 8; mt++)
#pragma unroll
            for (int ot = 0; ot < 2; ot++) {
                int o = wv * 32 + ot * 16 + lc;
                float bs = bias[o];
#pragma unroll
                for (int r = 0; r < 4; r++) {
                    int n = n0 + mt * 16 + lg * 4 + r;
                    float v = acc[mt][ot][r] + bs;
                    unsigned short h = bf16_rne(v);
                    size_t idx = ((size_t)b * 4096 + n) * 128 + o;
                    outH[idx] = h;
                    outL[idx] = bf16_rne(v - bf16_to_f32(h));
                }
            }
    } else {
        const int mbase = blockIdx.x * 32;
#pragma unroll
        for (int mt = 0; mt < 4; mt++)
#pragma unroll
            for (int ot = 0; ot < 2; ot++) {
                int o = wv * 32 + ot * 16 + lc;
                float bs = bias[o];
#pragma unroll
                for (int pair = 0; pair < 2; pair++) {
                    float v = fmaxf(fmaxf(acc[mt][ot][2 * pair], acc[mt][ot][2 * pair + 1]),
                                    fmaxf(acc[mt + 4][ot][2 * pair], acc[mt + 4][ot][2 * pair + 1])) + bs;
                    int pw = mt * 8 + lg * 2 + pair;
                    int m  = mbase + pw;
                    if (MODE == 1) {
                        unsigned short h = bf16_rne(v);
                        size_t idx = ((size_t)b * 1024 + m) * 128 + o;
                        outH[idx] = h;
                        outL[idx] = bf16_rne(v - bf16_to_f32(h));
                    } else {
                        outH[((size_t)b * 128 + o) * 1024 + m] = bf16_rne(v);
                    }
                }
            }
    }
}

// ---------------------------------------------------------------------------
// Flash attention v5: block = 64 Q rows (4 waves x 16 rows), grid 1024 =
// 4 blocks/CU (LDS 37 KB, VGPR <= 128). XCD-swizzled: XCD i owns batches
// {2i,2i+1} -> K/V L2-resident. K hi+lo in 32-row tiles, double-buffered via
// global_load_lds with XOR swizzle (zero staging VGPRs). QK^T = hh+hl+lh
// split-bf16 (~fp32 logits). Online softmax in registers. P in per-wave
// pad-40 LDS (uniform bank spread); V read direct from L2.
// ---------------------------------------------------------------------------
__global__ __launch_bounds__(256, 4) void attn_kernel(
    const unsigned short* __restrict__ thH,  // [16][4096][128]
    const unsigned short* __restrict__ thL,
    const unsigned short* __restrict__ phH,  // [16][1024][128]
    const unsigned short* __restrict__ phL,
    const unsigned short* __restrict__ gp,   // [16][128][1024]  (V^T)
    unsigned short* __restrict__ y)          // [16][4096][128]
{
    // XCD-aware bijective swizzle: fid%8 = XCD; XCD i gets batches {2i,2i+1}
    const int fid  = blockIdx.x + (blockIdx.y << 6);   // grid (64,16) -> 0..1023
    const int xcd  = fid & 7;
    const int slot = fid >> 3;                          // 0..127
    const int b    = 2 * xcd + (slot >> 6);
    const int n0   = (slot & 63) * 64;

    const int tid = threadIdx.x;
    const int wv  = tid >> 6;
    const int l   = tid & 63;
    const int lg  = l >> 4;
    const int lc  = l & 15;

    __shared__ __align__(16) unsigned short Kh[2][32 * 128];  // 16 KB
    __shared__ __align__(16) unsigned short Kl[2][32 * 128];  // 16 KB
    __shared__ __align__(16) unsigned short Pb[4][16 * 40];   //  5 KB

    const unsigned short* phHb = phH + (size_t)b * 1024 * 128;
    const unsigned short* phLb = phL + (size_t)b * 1024 * 128;
    const unsigned short* gpb  = gp  + (size_t)b * 128 * 1024;
    unsigned short* Pw = Pb[wv];

    // ---- Q fragments: rows n0 + wv*16 + lc ----
    s16x8 qh[4], ql[4];
    {
        const size_t qrow = ((size_t)b * 4096 + n0 + wv * 16 + lc) * 128;
#pragma unroll
        for (int ks = 0; ks < 4; ks++) {
            qh[ks] = *(const s16x8*)(thH + qrow + ks * 32 + lg * 8);
            ql[ks] = *(const s16x8*)(thL + qrow + ks * 32 + lg * 8);
        }
    }

    f32x4 O[8];
#pragma unroll
    for (int t = 0; t < 8; t++) O[t] = (f32x4){0.f, 0.f, 0.f, 0.f};
    float mrun[4] = {-1e30f, -1e30f, -1e30f, -1e30f};
    float lrun[4] = {0.f, 0.f, 0.f, 0.f};

    const int lr  = l >> 4;   // staging row-within-4
    const int sc_ = l & 15;   // staging slot

    // wave wv stages rows [wv*8, wv*8+8) of a 32-row tile (hi+lo planes)
#define STAGE(buf, kt_)                                                              \
    {                                                                                \
        _Pragma("unroll")                                                            \
        for (int t = 0; t < 2; t++) {                                                \
            int Rt = wv * 8 + t * 4;                                                 \
            int R  = Rt + lr;                                                        \
            int ck = sc_ ^ (R & 15);                                                 \
            size_t src = ((size_t)((kt_) * 32 + R)) * 128 + ck * 8;                  \
            async_copy16(&Kh[buf][Rt * 128], phHb + src);                            \
            async_copy16(&Kl[buf][Rt * 128], phLb + src);                            \
        }                                                                            \
    }

    STAGE(0, 0);

    for (int kt = 0; kt < 32; kt++) {
        const int cur = kt & 1;
        __syncthreads();                 // vmcnt(0) drain -> tile kt visible
        if (kt < 31) STAGE(cur ^ 1, kt + 1);

        const unsigned short* KhT = Kh[cur];
        const unsigned short* KlT = Kl[cur];

        // ---- QK^T: 16 rows x 32 cols, split-bf16 (hh+hl+lh) ----
        f32x4 s[2];
#pragma unroll
        for (int ct = 0; ct < 2; ct++) s[ct] = (f32x4){0.f, 0.f, 0.f, 0.f};
#pragma unroll
        for (int ct = 0; ct < 2; ct++) {
            const int row = ct * 16 + lc;
#pragma unroll
            for (int ks = 0; ks < 4; ks++) {
                const int slt = (ks * 4 + lg) ^ lc;
                s16x8 kh = *(const s16x8*)(KhT + row * 128 + slt * 8);
                s16x8 kl = *(const s16x8*)(KlT + row * 128 + slt * 8);
                s[ct] = __builtin_amdgcn_mfma_f32_16x16x32_bf16(qh[ks], kh, s[ct], 0, 0, 0);
                s[ct] = __builtin_amdgcn_mfma_f32_16x16x32_bf16(qh[ks], kl, s[ct], 0, 0, 0);
                s[ct] = __builtin_amdgcn_mfma_f32_16x16x32_bf16(ql[ks], kh, s[ct], 0, 0, 0);
            }
        }

        // ---- online softmax (rows = lg*4 + r) ----
        float tm[4];
#pragma unroll
        for (int r = 0; r < 4; r++) tm[r] = fmaxf(s[0][r], s[1][r]);
#pragma unroll
        for (int d = 1; d < 16; d <<= 1)
#pragma unroll
            for (int r = 0; r < 4; r++) tm[r] = fmaxf(tm[r], __shfl_xor(tm[r], d, 64));

        bool grow = (tm[0] > mrun[0]) || (tm[1] > mrun[1]) ||
                    (tm[2] > mrun[2]) || (tm[3] > mrun[3]);
        if (__any(grow)) {
            float scv[4];
#pragma unroll
            for (int r = 0; r < 4; r++) {
                float mn = fmaxf(mrun[r], tm[r]);
                scv[r] = __expf(mrun[r] - mn);
                mrun[r] = mn;
                lrun[r] *= scv[r];
            }
#pragma unroll
            for (int t = 0; t < 8; t++)
#pragma unroll
                for (int r = 0; r < 4; r++) O[t][r] *= scv[r];
        }

        float ts[4] = {0.f, 0.f, 0.f, 0.f};
#pragma unroll
        for (int ct = 0; ct < 2; ct++)
#pragma unroll
            for (int r = 0; r < 4; r++) {
                float e = __expf(s[ct][r] - mrun[r]);
                s[ct][r] = e;
                ts[r] += e;
            }
#pragma unroll
        for (int d = 1; d < 16; d <<= 1)
#pragma unroll
            for (int r = 0; r < 4; r++) ts[r] += __shfl_xor(ts[r], d, 64);
#pragma unroll
        for (int r = 0; r < 4; r++) lrun[r] += ts[r];

        // ---- P -> per-wave LDS [16][40] (pad-40 => uniform banks) ----
#pragma unroll
        for (int ct = 0; ct < 2; ct++)
#pragma unroll
            for (int r = 0; r < 4; r++)
                Pw[(lg * 4 + r) * 40 + ct * 16 + lc] = bf16_rne(s[ct][r]);

        // ---- PV: O += P(16x32) * V(32x128), V direct from L2 ----
        const int mt = kt * 32;
        s16x8 pa = *(const s16x8*)(Pw + lc * 40 + lg * 8);
#pragma unroll
        for (int ci_t = 0; ci_t < 8; ci_t++) {
            s16x8 vb = *(const s16x8*)(gpb + (size_t)(ci_t * 16 + lc) * 1024 + mt + lg * 8);
            O[ci_t] = __builtin_amdgcn_mfma_f32_16x16x32_bf16(pa, vb, O[ci_t], 0, 0, 0);
        }
    }

    // ---- epilogue: normalize and store ----
#pragma unroll
    for (int r = 0; r < 4; r++) {
        float inv = 1.0f / lrun[r];
        int n = n0 + wv * 16 + lg * 4 + r;
        size_t base = ((size_t)b * 4096 + n) * 128;
#pragma unroll
        for (int ci_t = 0; ci_t < 8; ci_t++)
            y[base + ci_t * 16 + lc] = bf16_rne(O[ci_t][r] * inv);
    }
#undef STAGE
}

// ---------------------------------------------------------------------------
// W conv: W_y[b][o][n] = sum_ci W_w[o][ci] * y[b][n][ci] + W_b[o]   (bf16 out)
// ---------------------------------------------------------------------------
__global__ __launch_bounds__(256) void wconv_kernel(
    const unsigned short* __restrict__ y,   // [16][4096][128]
    const float* __restrict__ Ww,           // [256][128]
    const float* __restrict__ Wb,           // [256]
    unsigned short* __restrict__ wy)        // [16][256][4096]
{
    const int b   = blockIdx.z;
    const int o0  = blockIdx.x * 64;
    const int nb  = blockIdx.y * 256;
    const int tid = threadIdx.x;
    const int wv  = tid >> 6;
    const int l   = tid & 63;
    const int lg  = l >> 4;
    const int lc  = l & 15;
    const int n0  = nb + wv * 64;

    f32x4 acc[4][4];
#pragma unroll
    for (int i = 0; i < 4; i++)
#pragma unroll
        for (int j = 0; j < 4; j++) acc[i][j] = (f32x4){0.f, 0.f, 0.f, 0.f};

#pragma unroll
    for (int ks = 0; ks < 4; ks++) {
        s16x8 a[4];
#pragma unroll
        for (int ot = 0; ot < 4; ot++) {
            const float* wp = Ww + (size_t)(o0 + ot * 16 + lc) * 128 + ks * 32 + lg * 8;
#pragma unroll
            for (int j = 0; j < 8; j++) a[ot][j] = (short)bf16_rne(wp[j]);
        }
#pragma unroll
        for (int nt = 0; nt < 4; nt++) {
            s16x8 bf = *(const s16x8*)(y + ((size_t)b * 4096 + n0 + nt * 16 + lc) * 128 + ks * 32 + lg * 8);
#pragma unroll
            for (int ot = 0; ot < 4; ot++)
                acc[ot][nt] = __builtin_amdgcn_mfma_f32_16x16x32_bf16(a[ot], bf, acc[ot][nt], 0, 0, 0);
        }
    }
#pragma unroll
    for (int ot = 0; ot < 4; ot++) {
#pragma unroll
        for (int r = 0; r < 4; r++) {
            int o = o0 + ot * 16 + lg * 4 + r;
            float bsv = Wb[o];
#pragma unroll
            for (int nt = 0; nt < 4; nt++) {
                float v = acc[ot][nt][r] + bsv;
                wy[((size_t)b * 256 + o) * 4096 + n0 + nt * 16 + lc] = bf16_rne(v);
            }
        }
    }
}

// ---------------------------------------------------------------------------
__global__ __launch_bounds__(256) void stats_kernel(
    const unsigned short* __restrict__ wy,  // [16][256][4096]
    const float* __restrict__ gamma, const float* __restrict__ beta,
    float* __restrict__ scale, float* __restrict__ shift)
{
    const int o = blockIdx.x;
    const int t = threadIdx.x;
    float s1 = 0.f, s2 = 0.f;
    for (int b = 0; b < 16; b++) {
        const unsigned short* p = wy + ((size_t)b * 256 + o) * 4096;
#pragma unroll
        for (int i = 0; i < 4; i++) {
            uint2 u = *(const uint2*)(p + i * 1024 + t * 4);
            float v0 = bf16_to_f32((unsigned short)(u.x & 0xffff));
            float v1 = bf16_to_f32((unsigned short)(u.x >> 16));
            float v2 = bf16_to_f32((unsigned short)(u.y & 0xffff));
            float v3 = bf16_to_f32((unsigned short)(u.y >> 16));
            s1 += v0 + v1 + v2 + v3;
            s2 += v0 * v0 + v1 * v1 + v2 * v2 + v3 * v3;
        }
    }
#pragma unroll
    for (int d = 1; d < 64; d <<= 1) { s1 += __shfl_xor(s1, d, 64); s2 += __shfl_xor(s2, d, 64); }
    __shared__ float rs1[4], rs2[4];
    if ((t & 63) == 0) { rs1[t >> 6] = s1; rs2[t >> 6] = s2; }
    __syncthreads();
    if (t == 0) {
        float S1 = rs1[0] + rs1[1] + rs1[2] + rs1[3];
        float S2 = rs2[0] + rs2[1] + rs2[2] + rs2[3];
        const float cnt = 16.0f * 4096.0f;
        float mean = S1 / cnt;
        float var  = S2 / cnt - mean * mean;
        float sc = gamma[o] * rsqrtf(var + 1e-5f);
        scale[o] = sc;
        shift[o] = beta[o] - mean * sc;
    }
}

// ---------------------------------------------------------------------------
__global__ __launch_bounds__(256) void final_kernel(
    const unsigned short* __restrict__ wy,
    const float* __restrict__ x,
    const float* __restrict__ scale, const float* __restrict__ shift,
    const float* __restrict__ inp0,
    float* __restrict__ out)
{
    if (blockIdx.x == 0 && threadIdx.x == 0) out[0] = inp0[0];
    float* z = out + 1;
    const size_t total4 = (size_t)16 * 256 * 4096 / 4;
    for (size_t v = (size_t)blockIdx.x * 256 + threadIdx.x; v < total4; v += (size_t)gridDim.x * 256) {
        size_t e = v * 4;
        int c = (int)((e >> 12) & 255);
        uint2 u = *(const uint2*)(wy + e);
        float4 xv = *(const float4*)(x + e);
        float sc = scale[c], sh = shift[c];
        float z0 = sc * bf16_to_f32((unsigned short)(u.x & 0xffff)) + sh + xv.x;
        float z1 = sc * bf16_to_f32((unsigned short)(u.x >> 16))    + sh + xv.y;
        float z2 = sc * bf16_to_f32((unsigned short)(u.y & 0xffff)) + sh + xv.z;
        float z3 = sc * bf16_to_f32((unsigned short)(u.y >> 16))    + sh + xv.w;
        z[e + 0] = z0; z[e + 1] = z1; z[e + 2] = z2; z[e + 3] = z3;
    }
}

// ---------------------------------------------------------------------------
extern "C" void kernel_launch(void* const* d_in, const int* in_sizes, int n_in,
                              void* d_out, int out_size, void* d_ws, size_t ws_size,
                              hipStream_t stream) {
    const float* inp0  = (const float*)d_in[0];
    const float* x     = (const float*)d_in[1];
    const float* g_w   = (const float*)d_in[2];
    const float* g_b   = (const float*)d_in[3];
    const float* th_w  = (const float*)d_in[4];
    const float* th_b  = (const float*)d_in[5];
    const float* ph_w  = (const float*)d_in[6];
    const float* ph_b  = (const float*)d_in[7];
    const float* W_w   = (const float*)d_in[8];
    const float* W_b   = (const float*)d_in[9];
    const float* gamma = (const float*)d_in[10];
    const float* beta  = (const float*)d_in[11];

    char* ws = (char*)d_ws;
    const size_t MB = 1048576;
    unsigned short* thH = (unsigned short*)(ws);                  // 16 MB
    unsigned short* thL = (unsigned short*)(ws + 16 * MB);        // 16 MB
    unsigned short* phH = (unsigned short*)(ws + 32 * MB);        // 4 MB
    unsigned short* phL = (unsigned short*)(ws + 36 * MB);        // 4 MB
    unsigned short* gpv = (unsigned short*)(ws + 40 * MB);        // 4 MB
    unsigned short* yv  = (unsigned short*)(ws + 44 * MB);        // 16 MB
    unsigned short* wy  = (unsigned short*)(ws + 60 * MB);        // 32 MB
    float* scaleb       = (float*)(ws + 92 * MB);                 // 1 KB
    float* shiftb       = (float*)(ws + 92 * MB + 1024);          // 1 KB

    conv_kernel<0><<<dim3(32, 16), 256, 0, stream>>>(x, th_w, th_b, thH, thL);
    conv_kernel<1><<<dim3(32, 16), 256, 0, stream>>>(x, ph_w, ph_b, phH, phL);
    conv_kernel<2><<<dim3(32, 16), 256, 0, stream>>>(x, g_w, g_b, gpv, gpv);
    attn_kernel<<<dim3(64, 16), 256, 0, stream>>>(thH, thL, phH, phL, gpv, yv);
    wconv_kernel<<<dim3(4, 16, 16), 256, 0, stream>>>(yv, W_w, W_b, wy);
    stats_kernel<<<dim3(256), 256, 0, stream>>>(wy, gamma, beta, scaleb, shiftb);
    final_kernel<<<dim3(2048), 256, 0, stream>>>(wy, x, scaleb, shiftb, inp0, (float*)d_out);
}

// Round 8
// 401.975 us; speedup vs baseline: 1.5231x; 1.0419x over previous
//
#include <hip/hip_runtime.h>
#include <stdint.h>

typedef __attribute__((ext_vector_type(4))) float f32x4;
typedef __attribute__((ext_vector_type(8))) short s16x8;

// ---------- bf16 helpers ----------
__device__ __forceinline__ unsigned short bf16_rne(float f) {
    union { float f; unsigned u; } v; v.f = f;
    return (unsigned short)((v.u + 0x7fffu + ((v.u >> 16) & 1u)) >> 16);
}
__device__ __forceinline__ float bf16_to_f32(unsigned short h) {
    union { unsigned u; float f; } v; v.u = ((unsigned)h) << 16;
    return v.f;
}

// async global->LDS 16B per lane. LDS dest must be wave-uniform base (+lane*16).
__device__ __forceinline__ void async_copy16(unsigned short* lds, const unsigned short* glb) {
    __builtin_amdgcn_global_load_lds(
        (const __attribute__((address_space(1))) unsigned int*)(glb),
        (__attribute__((address_space(3))) unsigned int*)(lds),
        16, 0, 0);
}

// Problem dims: B=16, C=256, CI=128, H=W=64, N=4096, NP=1024 (pooled 32x32)

// ---------------------------------------------------------------------------
// conv1x1 kernel. MODE 0: theta (no pool, split hi/lo out [b][n][o])
//                 MODE 1: phi   (pool,  split hi/lo out [b][m][o])
//                 MODE 2: g     (pool,  single     out [b][o][m])
// Staging pair-packs 2 channels -> b32 LDS writes.
// ---------------------------------------------------------------------------
template<int MODE>
__global__ __launch_bounds__(256) void conv_kernel(
    const float* __restrict__ x,      // [16][256][4096]
    const float* __restrict__ w,      // [128][256]
    const float* __restrict__ bias,   // [128]
    unsigned short* __restrict__ outH,
    unsigned short* __restrict__ outL)
{
    const int b   = blockIdx.y;
    const int n0  = blockIdx.x * 128;
    const int tid = threadIdx.x;
    const int wv  = tid >> 6;
    const int l   = tid & 63;
    const int lg  = l >> 4;   // lane group 0..3
    const int lc  = l & 15;   // lane col  0..15

    __shared__ __align__(16) unsigned short Ah[128][40];
    __shared__ __align__(16) unsigned short Al[128][40];

    f32x4 acc[8][2];
#pragma unroll
    for (int i = 0; i < 8; i++)
#pragma unroll
        for (int j = 0; j < 2; j++) acc[i][j] = (f32x4){0.f, 0.f, 0.f, 0.f};

    for (int kc = 0; kc < 256; kc += 32) {
        __syncthreads();
#pragma unroll
        for (int i = 0; i < 8; i++) {
            int lin = i * 256 + tid;     // 0..2047
            int cp  = lin >> 7;          // 0..15 -> cc = 2*cp
            int nn  = lin & 127;
            const float* xp = x + ((size_t)b * 256 + (kc + 2 * cp)) * 4096 + n0 + nn;
            float v0 = xp[0];
            float v1 = xp[4096];
            unsigned short h0 = bf16_rne(v0), h1 = bf16_rne(v1);
            *(unsigned*)&Ah[nn][2 * cp] = (unsigned)h0 | ((unsigned)h1 << 16);
            if (MODE != 2) {
                unsigned short l0 = bf16_rne(v0 - bf16_to_f32(h0));
                unsigned short l1 = bf16_rne(v1 - bf16_to_f32(h1));
                *(unsigned*)&Al[nn][2 * cp] = (unsigned)l0 | ((unsigned)l1 << 16);
            }
        }
        __syncthreads();

        s16x8 wh[2], wl[2];
#pragma unroll
        for (int ot = 0; ot < 2; ot++) {
            int orow = wv * 32 + ot * 16 + lc;
            const float* wp = w + (size_t)orow * 256 + kc + lg * 8;
#pragma unroll
            for (int j = 0; j < 8; j++) {
                float wvv = wp[j];
                unsigned short h = bf16_rne(wvv);
                wh[ot][j] = (short)h;
                if (MODE != 2) wl[ot][j] = (short)bf16_rne(wvv - bf16_to_f32(h));
            }
        }

#pragma unroll
        for (int mt = 0; mt < 8; mt++) {
            s16x8 ah = *(const s16x8*)&Ah[mt * 16 + lc][lg * 8];
            s16x8 al;
            if (MODE != 2) al = *(const s16x8*)&Al[mt * 16 + lc][lg * 8];
#pragma unroll
            for (int ot = 0; ot < 2; ot++) {
                acc[mt][ot] = __builtin_amdgcn_mfma_f32_16x16x32_bf16(ah, wh[ot], acc[mt][ot], 0, 0, 0);
                if (MODE != 2) {
                    acc[mt][ot] = __builtin_amdgcn_mfma_f32_16x16x32_bf16(ah, wl[ot], acc[mt][ot], 0, 0, 0);
                    acc[mt][ot] = __builtin_amdgcn_mfma_f32_16x16x32_bf16(al, wh[ot], acc[mt][ot], 0, 0, 0);
                }
            }
        }
    }

    if (MODE == 0) {
#pragma unroll
        for (int mt = 0; mt < 8; mt++)
#pragma unroll
            for (int ot = 0; ot < 2; ot++) {
                int o = wv * 32 + ot * 16 + lc;
                float bs = bias[o];
#pragma unroll
                for (int r = 0; r < 4; r++) {
                    int n = n0 + mt * 16 + lg * 4 + r;
                    float v = acc[mt][ot][r] + bs;
                    unsigned short h = bf16_rne(v);
                    size_t idx = ((size_t)b * 4096 + n) * 128 + o;
                    outH[idx] = h;
                    outL[idx] = bf16_rne(v - bf16_to_f32(h));
                }
            }
    } else {
        const int mbase = blockIdx.x * 32;
#pragma unroll
        for (int mt = 0; mt < 4; mt++)
#pragma unroll
            for (int ot = 0; ot < 2; ot++) {
                int o = wv * 32 + ot * 16 + lc;
                float bs = bias[o];
#pragma unroll
                for (int pair = 0; pair < 2; pair++) {
                    float v = fmaxf(fmaxf(acc[mt][ot][2 * pair], acc[mt][ot][2 * pair + 1]),
                                    fmaxf(acc[mt + 4][ot][2 * pair], acc[mt + 4][ot][2 * pair + 1])) + bs;
                    int pw = mt * 8 + lg * 2 + pair;
                    int m  = mbase + pw;
                    if (MODE == 1) {
                        unsigned short h = bf16_rne(v);
                        size_t idx = ((size_t)b * 1024 + m) * 128 + o;
                        outH[idx] = h;
                        outL[idx] = bf16_rne(v - bf16_to_f32(h));
                    } else {
                        outH[((size_t)b * 128 + o) * 1024 + m] = bf16_rne(v);
                    }
                }
            }
    }
}

// ---------------------------------------------------------------------------
// Flash attention v6: swapped QK^T (S^T = K*Q^T) makes each lane own all 32
// logits of ONE q-row (lc) -> softmax reduce = in-register + 2 shfl_xor
// (was 32 ds_swizzles). P packed as b64 writes (was 8 scalar). Block = 64 Q
// rows (4 waves x 16), grid 1024 = 4/CU, LDS 37 KB, XCD batch swizzle.
// K hi+lo 32-row tiles double-buffered via global_load_lds with XOR swizzle.
// ---------------------------------------------------------------------------
__global__ __launch_bounds__(256, 4) void attn_kernel(
    const unsigned short* __restrict__ thH,  // [16][4096][128]
    const unsigned short* __restrict__ thL,
    const unsigned short* __restrict__ phH,  // [16][1024][128]
    const unsigned short* __restrict__ phL,
    const unsigned short* __restrict__ gp,   // [16][128][1024]  (V^T)
    unsigned short* __restrict__ y)          // [16][4096][128]
{
    // XCD-aware bijective swizzle: fid%8 = XCD; XCD i gets batches {2i,2i+1}
    const int fid  = blockIdx.x + (blockIdx.y << 6);   // grid (64,16) -> 0..1023
    const int xcd  = fid & 7;
    const int slot = fid >> 3;                          // 0..127
    const int b    = 2 * xcd + (slot >> 6);
    const int n0   = (slot & 63) * 64;

    const int tid = threadIdx.x;
    const int wv  = tid >> 6;
    const int l   = tid & 63;
    const int lg  = l >> 4;
    const int lc  = l & 15;

    __shared__ __align__(16) unsigned short Kh[2][32 * 128];  // 16 KB
    __shared__ __align__(16) unsigned short Kl[2][32 * 128];  // 16 KB
    __shared__ __align__(16) unsigned short Pb[4][16 * 40];   //  5 KB

    const unsigned short* phHb = phH + (size_t)b * 1024 * 128;
    const unsigned short* phLb = phL + (size_t)b * 1024 * 128;
    const unsigned short* gpb  = gp  + (size_t)b * 128 * 1024;
    unsigned short* Pw = Pb[wv];

    // ---- Q fragments: rows n0 + wv*16 + lc (B-operand layout == A layout) ----
    s16x8 qh[4], ql[4];
    {
        const size_t qrow = ((size_t)b * 4096 + n0 + wv * 16 + lc) * 128;
#pragma unroll
        for (int ks = 0; ks < 4; ks++) {
            qh[ks] = *(const s16x8*)(thH + qrow + ks * 32 + lg * 8);
            ql[ks] = *(const s16x8*)(thL + qrow + ks * 32 + lg * 8);
        }
    }

    f32x4 O[8];
#pragma unroll
    for (int t = 0; t < 8; t++) O[t] = (f32x4){0.f, 0.f, 0.f, 0.f};
    float mrun = -1e30f;   // running max of q-row lc
    float lrun = 0.f;      // running sum of q-row lc

    const int lr  = l >> 4;   // staging row-within-4
    const int sc_ = l & 15;   // staging slot

    // wave wv stages rows [wv*8, wv*8+8) of a 32-row tile (hi+lo planes)
#define STAGE(buf, kt_)                                                              \
    {                                                                                \
        _Pragma("unroll")                                                            \
        for (int t = 0; t < 2; t++) {                                                \
            int Rt = wv * 8 + t * 4;                                                 \
            int R  = Rt + lr;                                                        \
            int ck = sc_ ^ (R & 15);                                                 \
            size_t src = ((size_t)((kt_) * 32 + R)) * 128 + ck * 8;                  \
            async_copy16(&Kh[buf][Rt * 128], phHb + src);                            \
            async_copy16(&Kl[buf][Rt * 128], phLb + src);                            \
        }                                                                            \
    }

    STAGE(0, 0);

    for (int kt = 0; kt < 32; kt++) {
        const int cur = kt & 1;
        __syncthreads();                 // vmcnt(0) drain -> tile kt visible
        if (kt < 31) STAGE(cur ^ 1, kt + 1);

        const unsigned short* KhT = Kh[cur];
        const unsigned short* KlT = Kl[cur];

        // ---- swapped QK^T: S^T[k][q], A = K-tile rows, B = Q regs ----
        // D layout: col(lane&15) = q-row, row((lane>>4)*4+r + ct*16) = k-pos
        f32x4 s[2];
#pragma unroll
        for (int ct = 0; ct < 2; ct++) s[ct] = (f32x4){0.f, 0.f, 0.f, 0.f};
#pragma unroll
        for (int ct = 0; ct < 2; ct++) {
            const int row = ct * 16 + lc;
#pragma unroll
            for (int ks = 0; ks < 4; ks++) {
                const int slt = (ks * 4 + lg) ^ lc;
                s16x8 kh = *(const s16x8*)(KhT + row * 128 + slt * 8);
                s16x8 kl = *(const s16x8*)(KlT + row * 128 + slt * 8);
                s[ct] = __builtin_amdgcn_mfma_f32_16x16x32_bf16(kh, qh[ks], s[ct], 0, 0, 0);
                s[ct] = __builtin_amdgcn_mfma_f32_16x16x32_bf16(kl, qh[ks], s[ct], 0, 0, 0);
                s[ct] = __builtin_amdgcn_mfma_f32_16x16x32_bf16(kh, ql[ks], s[ct], 0, 0, 0);
            }
        }

        // ---- lane-local online softmax (lane owns 8 logits of row lc) ----
        float tm = fmaxf(fmaxf(fmaxf(s[0][0], s[0][1]), fmaxf(s[0][2], s[0][3])),
                         fmaxf(fmaxf(s[1][0], s[1][1]), fmaxf(s[1][2], s[1][3])));
        tm = fmaxf(tm, __shfl_xor(tm, 16, 64));
        tm = fmaxf(tm, __shfl_xor(tm, 32, 64));

        if (__any(tm > mrun)) {
            float mn  = fmaxf(mrun, tm);
            float scr = __expf(mrun - mn);   // rescale for q-row lc
            mrun = mn;
            lrun *= scr;
            // O rows are lg*4+r -> fetch that row's scale via bpermute
            float scO[4];
#pragma unroll
            for (int r = 0; r < 4; r++) scO[r] = __shfl(scr, lg * 4 + r, 64);
#pragma unroll
            for (int t = 0; t < 8; t++)
#pragma unroll
                for (int r = 0; r < 4; r++) O[t][r] *= scO[r];
        }

        float ts = 0.f;
        float p[8];
#pragma unroll
        for (int ct = 0; ct < 2; ct++)
#pragma unroll
            for (int r = 0; r < 4; r++) {
                float e = __expf(s[ct][r] - mrun);
                p[ct * 4 + r] = e;
                ts += e;
            }
        ts += __shfl_xor(ts, 16, 64);
        ts += __shfl_xor(ts, 32, 64);
        lrun += ts;

        // ---- P -> LDS: row = q (lc), cols kk = ct*16 + lg*4 + {0..3} ----
        // 2x b64 packed writes (8-byte aligned: 80*lc + 32*ct + 8*lg)
#pragma unroll
        for (int ct = 0; ct < 2; ct++) {
            unsigned w0 = (unsigned)bf16_rne(p[ct * 4 + 0]) | ((unsigned)bf16_rne(p[ct * 4 + 1]) << 16);
            unsigned w1 = (unsigned)bf16_rne(p[ct * 4 + 2]) | ((unsigned)bf16_rne(p[ct * 4 + 3]) << 16);
            uint2 pk; pk.x = w0; pk.y = w1;
            *(uint2*)&Pw[lc * 40 + ct * 16 + lg * 4] = pk;
        }

        // ---- PV: O += P(16x32) * V(32x128), V direct from L2 ----
        const int mt = kt * 32;
        s16x8 pa = *(const s16x8*)(Pw + lc * 40 + lg * 8);
#pragma unroll
        for (int ci_t = 0; ci_t < 8; ci_t++) {
            s16x8 vb = *(const s16x8*)(gpb + (size_t)(ci_t * 16 + lc) * 1024 + mt + lg * 8);
            O[ci_t] = __builtin_amdgcn_mfma_f32_16x16x32_bf16(pa, vb, O[ci_t], 0, 0, 0);
        }
    }

    // ---- epilogue: redistribute 1/lrun to O-row layout, store ----
    float invO[4];
#pragma unroll
    for (int r = 0; r < 4; r++) {
        float lr_ = __shfl(lrun, lg * 4 + r, 64);
        invO[r] = 1.0f / lr_;
    }
#pragma unroll
    for (int r = 0; r < 4; r++) {
        int n = n0 + wv * 16 + lg * 4 + r;
        size_t base = ((size_t)b * 4096 + n) * 128;
#pragma unroll
        for (int ci_t = 0; ci_t < 8; ci_t++)
            y[base + ci_t * 16 + lc] = bf16_rne(O[ci_t][r] * invO[r]);
    }
#undef STAGE
}

// ---------------------------------------------------------------------------
// W conv: W_y[b][o][n] = sum_ci W_w[o][ci] * y[b][n][ci] + W_b[o]   (bf16 out)
// ---------------------------------------------------------------------------
__global__ __launch_bounds__(256) void wconv_kernel(
    const unsigned short* __restrict__ y,   // [16][4096][128]
    const float* __restrict__ Ww,           // [256][128]
    const float* __restrict__ Wb,           // [256]
    unsigned short* __restrict__ wy)        // [16][256][4096]
{
    const int b   = blockIdx.z;
    const int o0  = blockIdx.x * 64;
    const int nb  = blockIdx.y * 256;
    const int tid = threadIdx.x;
    const int wv  = tid >> 6;
    const int l   = tid & 63;
    const int lg  = l >> 4;
    const int lc  = l & 15;
    const int n0  = nb + wv * 64;

    f32x4 acc[4][4];
#pragma unroll
    for (int i = 0; i < 4; i++)
#pragma unroll
        for (int j = 0; j < 4; j++) acc[i][j] = (f32x4){0.f, 0.f, 0.f, 0.f};

#pragma unroll
    for (int ks = 0; ks < 4; ks++) {
        s16x8 a[4];
#pragma unroll
        for (int ot = 0; ot < 4; ot++) {
            const float* wp = Ww + (size_t)(o0 + ot * 16 + lc) * 128 + ks * 32 + lg * 8;
#pragma unroll
            for (int j = 0; j < 8; j++) a[ot][j] = (short)bf16_rne(wp[j]);
        }
#pragma unroll
        for (int nt = 0; nt < 4; nt++) {
            s16x8 bf = *(const s16x8*)(y + ((size_t)b * 4096 + n0 + nt * 16 + lc) * 128 + ks * 32 + lg * 8);
#pragma unroll
            for (int ot = 0; ot < 4; ot++)
                acc[ot][nt] = __builtin_amdgcn_mfma_f32_16x16x32_bf16(a[ot], bf, acc[ot][nt], 0, 0, 0);
        }
    }
#pragma unroll
    for (int ot = 0; ot < 4; ot++) {
#pragma unroll
        for (int r = 0; r < 4; r++) {
            int o = o0 + ot * 16 + lg * 4 + r;
            float bsv = Wb[o];
#pragma unroll
            for (int nt = 0; nt < 4; nt++) {
                float v = acc[ot][nt][r] + bsv;
                wy[((size_t)b * 256 + o) * 4096 + n0 + nt * 16 + lc] = bf16_rne(v);
            }
        }
    }
}

// ---------------------------------------------------------------------------
__global__ __launch_bounds__(256) void stats_kernel(
    const unsigned short* __restrict__ wy,  // [16][256][4096]
    const float* __restrict__ gamma, const float* __restrict__ beta,
    float* __restrict__ scale, float* __restrict__ shift)
{
    const int o = blockIdx.x;
    const int t = threadIdx.x;
    float s1 = 0.f, s2 = 0.f;
    for (int b = 0; b < 16; b++) {
        const unsigned short* p = wy + ((size_t)b * 256 + o) * 4096;
#pragma unroll
        for (int i = 0; i < 4; i++) {
            uint2 u = *(const uint2*)(p + i * 1024 + t * 4);
            float v0 = bf16_to_f32((unsigned short)(u.x & 0xffff));
            float v1 = bf16_to_f32((unsigned short)(u.x >> 16));
            float v2 = bf16_to_f32((unsigned short)(u.y & 0xffff));
            float v3 = bf16_to_f32((unsigned short)(u.y >> 16));
            s1 += v0 + v1 + v2 + v3;
            s2 += v0 * v0 + v1 * v1 + v2 * v2 + v3 * v3;
        }
    }
#pragma unroll
    for (int d = 1; d < 64; d <<= 1) { s1 += __shfl_xor(s1, d, 64); s2 += __shfl_xor(s2, d, 64); }
    __shared__ float rs1[4], rs2[4];
    if ((t & 63) == 0) { rs1[t >> 6] = s1; rs2[t >> 6] = s2; }
    __syncthreads();
    if (t == 0) {
        float S1 = rs1[0] + rs1[1] + rs1[2] + rs1[3];
        float S2 = rs2[0] + rs2[1] + rs2[2] + rs2[3];
        const float cnt = 16.0f * 4096.0f;
        float mean = S1 / cnt;
        float var  = S2 / cnt - mean * mean;
        float sc = gamma[o] * rsqrtf(var + 1e-5f);
        scale[o] = sc;
        shift[o] = beta[o] - mean * sc;
    }
}

// ---------------------------------------------------------------------------
__global__ __launch_bounds__(256) void final_kernel(
    const unsigned short* __restrict__ wy,
    const float* __restrict__ x,
    const float* __restrict__ scale, const float* __restrict__ shift,
    const float* __restrict__ inp0,
    float* __restrict__ out)
{
    if (blockIdx.x == 0 && threadIdx.x == 0) out[0] = inp0[0];
    float* z = out + 1;
    const size_t total4 = (size_t)16 * 256 * 4096 / 4;
    for (size_t v = (size_t)blockIdx.x * 256 + threadIdx.x; v < total4; v += (size_t)gridDim.x * 256) {
        size_t e = v * 4;
        int c = (int)((e >> 12) & 255);
        uint2 u = *(const uint2*)(wy + e);
        float4 xv = *(const float4*)(x + e);
        float sc = scale[c], sh = shift[c];
        float z0 = sc * bf16_to_f32((unsigned short)(u.x & 0xffff)) + sh + xv.x;
        float z1 = sc * bf16_to_f32((unsigned short)(u.x >> 16))    + sh + xv.y;
        float z2 = sc * bf16_to_f32((unsigned short)(u.y & 0xffff)) + sh + xv.z;
        float z3 = sc * bf16_to_f32((unsigned short)(u.y >> 16))    + sh + xv.w;
        z[e + 0] = z0; z[e + 1] = z1; z[e + 2] = z2; z[e + 3] = z3;
    }
}

// ---------------------------------------------------------------------------
extern "C" void kernel_launch(void* const* d_in, const int* in_sizes, int n_in,
                              void* d_out, int out_size, void* d_ws, size_t ws_size,
                              hipStream_t stream) {
    const float* inp0  = (const float*)d_in[0];
    const float* x     = (const float*)d_in[1];
    const float* g_w   = (const float*)d_in[2];
    const float* g_b   = (const float*)d_in[3];
    const float* th_w  = (const float*)d_in[4];
    const float* th_b  = (const float*)d_in[5];
    const float* ph_w  = (const float*)d_in[6];
    const float* ph_b  = (const float*)d_in[7];
    const float* W_w   = (const float*)d_in[8];
    const float* W_b   = (const float*)d_in[9];
    const float* gamma = (const float*)d_in[10];
    const float* beta  = (const float*)d_in[11];

    char* ws = (char*)d_ws;
    const size_t MB = 1048576;
    unsigned short* thH = (unsigned short*)(ws);                  // 16 MB
    unsigned short* thL = (unsigned short*)(ws + 16 * MB);        // 16 MB
    unsigned short* phH = (unsigned short*)(ws + 32 * MB);        // 4 MB
    unsigned short* phL = (unsigned short*)(ws + 36 * MB);        // 4 MB
    unsigned short* gpv = (unsigned short*)(ws + 40 * MB);        // 4 MB
    unsigned short* yv  = (unsigned short*)(ws + 44 * MB);        // 16 MB
    unsigned short* wy  = (unsigned short*)(ws + 60 * MB);        // 32 MB
    float* scaleb       = (float*)(ws + 92 * MB);                 // 1 KB
    float* shiftb       = (float*)(ws + 92 * MB + 1024);          // 1 KB

    conv_kernel<0><<<dim3(32, 16), 256, 0, stream>>>(x, th_w, th_b, thH, thL);
    conv_kernel<1><<<dim3(32, 16), 256, 0, stream>>>(x, ph_w, ph_b, phH, phL);
    conv_kernel<2><<<dim3(32, 16), 256, 0, stream>>>(x, g_w, g_b, gpv, gpv);
    attn_kernel<<<dim3(64, 16), 256, 0, stream>>>(thH, thL, phH, phL, gpv, yv);
    wconv_kernel<<<dim3(4, 16, 16), 256, 0, stream>>>(yv, W_w, W_b, wy);
    stats_kernel<<<dim3(256), 256, 0, stream>>>(wy, gamma, beta, scaleb, shiftb);
    final_kernel<<<dim3(2048), 256, 0, stream>>>(wy, x, scaleb, shiftb, inp0, (float*)d_out);
}